// Round 12
// baseline (428.627 us; speedup 1.0000x reference)
//
#include <hip/hip_runtime.h>
#include <math.h>

#define NROWS 16384   // B*T
#define INCH  512
#define CH    2048
#define DD    256
#define MM    1024

typedef unsigned short u16;
typedef short short8 __attribute__((ext_vector_type(8)));
typedef float f32x4 __attribute__((ext_vector_type(4)));

__device__ __forceinline__ u16 f2bf(float f) {
  unsigned u = __float_as_uint(f);
  return (u16)((u + 0x7fffu + ((u >> 16) & 1u)) >> 16);
}
__device__ __forceinline__ float bf2f(u16 h) {
  return __uint_as_float(((unsigned)h) << 16);
}
__device__ __forceinline__ void gload16(const u16* g, u16* lds) {
  __builtin_amdgcn_global_load_lds((const __attribute__((address_space(1))) void*)g,
                                   (__attribute__((address_space(3))) void*)lds, 16, 0, 0);
}

// Coalesced-staging chunk mapping (16B chunks of 8 bf16 along K):
//   PC(row,kc) = (row>>4)*64 + (row&15)*4 + (kc ^ ((row>>1)&3))
//   frag read: chunk = group*64 + rI, rI = (lane&15)*4 + ((lane>>4)^((lane>>1)&3))

// src [R][C] fp32  ->  dh/dl [C][R] bf16 hi/lo   (transpose + split)
__global__ __launch_bounds__(256) void k_split_wT(const float* __restrict__ src,
                                                  u16* __restrict__ dh, u16* __restrict__ dl,
                                                  int R, int C) {
  __shared__ float t[32][33];
  const int tx = threadIdx.x & 31, ty = threadIdx.x >> 5;
  const int c0 = blockIdx.x * 32, r0 = blockIdx.y * 32;
#pragma unroll
  for (int i = 0; i < 4; ++i)
    t[ty + i * 8][tx] = src[(size_t)(r0 + ty + i * 8) * C + c0 + tx];
  __syncthreads();
#pragma unroll
  for (int i = 0; i < 4; ++i) {
    float v = t[tx][ty + i * 8];
    size_t o = (size_t)(c0 + ty + i * 8) * R + r0 + tx;
    u16 h = f2bf(v);
    dh[o] = h;
    dl[o] = f2bf(v - bf2f(h));
  }
}

// ---------------------------------------------------------------------------
// K1: H(split) = X @ W1.  Tile 256x256, BK=32, 512 thr (8 waves 2Mx4N),
// wave tile 128x64. A: fp32 global->reg->split->ds_write. B: pre-split W1^T
// via global_load_lds. LDS 128KB dbuf. Epilogue: 4x64-row slabs + row stats.
// ---------------------------------------------------------------------------
__global__ __launch_bounds__(512, 2) void k_gemm1(const float* __restrict__ X,
                                                  const u16* __restrict__ W1ht,
                                                  const u16* __restrict__ W1lt,
                                                  u16* __restrict__ Hh, u16* __restrict__ Hl,
                                                  float* __restrict__ STATS) {
  __shared__ u16 sm[2][4096 * 8];   // 128 KB
  const int tid = threadIdx.x;
  const int lane = tid & 63, w = tid >> 6;
  const int wr = w >> 2, wc = w & 3;
  const int gm = blockIdx.y * 256, n0 = blockIdx.x * 256;

  const int arow = tid >> 1, ahalf = tid & 1;
  const float* gx = X + ((size_t)(gm + arow) << 9) + ahalf * 16;
  const int axor = (arow >> 1) & 3;
  const int pcbase = (arow >> 4) * 64 + (arow & 15) * 4;

  f32x4 acc[8][4];
#pragma unroll
  for (int i = 0; i < 8; ++i)
#pragma unroll
    for (int j = 0; j < 4; ++j) acc[i][j] = (f32x4){0.f, 0.f, 0.f, 0.f};

  float a16[16];
  auto A_LOAD = [&](int kt) {
    const float* p = gx + kt * 32;
    *(float4*)&a16[0]  = *(const float4*)(p);
    *(float4*)&a16[4]  = *(const float4*)(p + 4);
    *(float4*)&a16[8]  = *(const float4*)(p + 8);
    *(float4*)&a16[12] = *(const float4*)(p + 12);
  };
  auto A_WRITE = [&](int buf) {
#pragma unroll
    for (int g = 0; g < 2; ++g) {
      const int kc = ahalf * 2 + g;
      unsigned hw[4], lw[4];
#pragma unroll
      for (int p = 0; p < 4; ++p) {
        const float v0 = a16[g * 8 + 2 * p], v1 = a16[g * 8 + 2 * p + 1];
        const u16 h0 = f2bf(v0), h1 = f2bf(v1);
        const u16 l0 = f2bf(v0 - bf2f(h0)), l1 = f2bf(v1 - bf2f(h1));
        hw[p] = (unsigned)h0 | ((unsigned)h1 << 16);
        lw[p] = (unsigned)l0 | ((unsigned)l1 << 16);
      }
      const int pc = pcbase + (kc ^ axor);
      *(uint4*)&sm[buf][(size_t)pc * 8] = make_uint4(hw[0], hw[1], hw[2], hw[3]);
      *(uint4*)&sm[buf][(size_t)(1024 + pc) * 8] = make_uint4(lw[0], lw[1], lw[2], lw[3]);
    }
  };
  auto B_STAGE = [&](int buf, int kt) {
#pragma unroll
    for (int t = 0; t < 4; ++t) {
      const int f = t * 512 + tid;            // [0,2048)
      const int mtx = f >> 10;
      const int wi = f & 1023;
      const int grp = wi >> 6, s2 = wi & 63;
      const int srow = n0 + grp * 16 + (s2 >> 2);
      const int k16 = (s2 & 3) ^ ((s2 >> 3) & 3);
      const u16* src = mtx ? W1lt : W1ht;
      gload16(src + ((size_t)srow << 9) + (kt << 5) + k16 * 8,
              &sm[buf][(size_t)(2048 + f) * 8]);
    }
  };

  A_LOAD(0);
  B_STAGE(0, 0);
  A_WRITE(0);

  const int lr = lane & 15;
  const int rI = lr * 4 + ((lane >> 4) ^ ((lr >> 1) & 3));
  for (int kt = 0; kt < 16; ++kt) {
    __syncthreads();
    if (kt + 1 < 16) {
      A_LOAD(kt + 1);
      B_STAGE((kt + 1) & 1, kt + 1);
    }
    const u16* base = sm[kt & 1];
    short8 bh[4], bl[4];
#pragma unroll
    for (int j = 0; j < 4; ++j) {
      bh[j] = *(const short8*)(base + (size_t)(2048 + (wc * 4 + j) * 64 + rI) * 8);
      bl[j] = *(const short8*)(base + (size_t)(3072 + (wc * 4 + j) * 64 + rI) * 8);
    }
#pragma unroll
    for (int i = 0; i < 8; ++i) {
      short8 ah = *(const short8*)(base + (size_t)((wr * 8 + i) * 64 + rI) * 8);
      short8 al = *(const short8*)(base + (size_t)(1024 + (wr * 8 + i) * 64 + rI) * 8);
#pragma unroll
      for (int j = 0; j < 4; ++j) {
        acc[i][j] = __builtin_amdgcn_mfma_f32_16x16x32_bf16(ah, bh[j], acc[i][j], 0, 0, 0);
        acc[i][j] = __builtin_amdgcn_mfma_f32_16x16x32_bf16(ah, bl[j], acc[i][j], 0, 0, 0);
        acc[i][j] = __builtin_amdgcn_mfma_f32_16x16x32_bf16(al, bh[j], acc[i][j], 0, 0, 0);
      }
    }
    if (kt + 1 < 16) A_WRITE((kt + 1) & 1);
  }

  // ---- epilogue: 4 slabs of 64 rows via fp32 [64][260] + row stats ----
  float* smf = (float*)&sm[0][0];
  const int rr = (lane >> 4) << 2, cc = lane & 15;
  const int lrow = tid >> 3, c0 = (tid & 7) * 32;
#pragma unroll
  for (int s = 0; s < 4; ++s) {
    __syncthreads();
    if (wr == (s >> 1)) {
      const int ib = (s & 1) * 4;
#pragma unroll
      for (int ii = 0; ii < 4; ++ii)
#pragma unroll
        for (int j = 0; j < 4; ++j)
#pragma unroll
          for (int reg = 0; reg < 4; ++reg)
            smf[(ii * 16 + rr + reg) * 260 + wc * 64 + j * 16 + cc] = acc[ib + ii][j][reg];
    }
    __syncthreads();
    const int grow = gm + s * 64 + lrow;
    float s1 = 0.f, ss = 0.f;
#pragma unroll
    for (int q = 0; q < 4; ++q) {
      float v[8];
      *(f32x4*)&v[0] = *(const f32x4*)&smf[lrow * 260 + c0 + q * 8];
      *(f32x4*)&v[4] = *(const f32x4*)&smf[lrow * 260 + c0 + q * 8 + 4];
#pragma unroll
      for (int e = 0; e < 8; ++e) { s1 += v[e]; ss += v[e] * v[e]; }
      unsigned hw[4], lw[4];
#pragma unroll
      for (int p = 0; p < 4; ++p) {
        const u16 h0 = f2bf(v[2 * p]), h1 = f2bf(v[2 * p + 1]);
        const u16 l0 = f2bf(v[2 * p] - bf2f(h0)), l1 = f2bf(v[2 * p + 1] - bf2f(h1));
        hw[p] = (unsigned)h0 | ((unsigned)h1 << 16);
        lw[p] = (unsigned)l0 | ((unsigned)l1 << 16);
      }
      const size_t o = (size_t)grow * CH + n0 + c0 + q * 8;
      *(uint4*)&Hh[o] = make_uint4(hw[0], hw[1], hw[2], hw[3]);
      *(uint4*)&Hl[o] = make_uint4(lw[0], lw[1], lw[2], lw[3]);
    }
#pragma unroll
    for (int m = 1; m <= 4; m <<= 1) { s1 += __shfl_xor(s1, m); ss += __shfl_xor(ss, m); }
    if ((tid & 7) == 0)
      *(float2*)&STATS[(size_t)grow * 16 + blockIdx.x * 2] = make_float2(s1, ss);
  }
}

// ---------------------------------------------------------------------------
// K2: reduce 8 slice-partials per row -> (mu, rinv)
// ---------------------------------------------------------------------------
__global__ __launch_bounds__(256) void k_rowstats(const float* __restrict__ STATS,
                                                  float2* __restrict__ MU2) {
  const int row = blockIdx.x * 256 + threadIdx.x;
  float s = 0.f, ss = 0.f;
#pragma unroll
  for (int i = 0; i < 8; ++i) {
    float2 p = *(const float2*)&STATS[((size_t)row << 4) + i * 2];
    s += p.x; ss += p.y;
  }
  const float mu = s * (1.f / CH);
  const float var = ss * (1.f / CH) - mu * mu;
  MU2[row] = make_float2(mu, 1.f / sqrtf(var + 1e-5f));
}

// ---------------------------------------------------------------------------
// K3: fused Z = relu(LN(H)) @ W2 + b2 -> per-head LSE -> Z, EXh/EXl, SELF.
// BARRIER-FREE / LDS-FREE K-loop: BM=64, BN=256, 512 thr (8 waves 2Mx4N,
// wave tile 32x64). A fragments read DIRECT from H (hi/lo) with in-register
// LN+ReLU+split (rows shared by 4 waves; dup VALU accepted). B fragments
// read DIRECT from L2-resident W2 split. No __syncthreads in the loop ->
// no vmcnt(0) drains; loads stay in flight across iterations.
// A prefetch depth 1 via named even/odd register sets (rule #20).
// ---------------------------------------------------------------------------
__global__ __launch_bounds__(512) void k_gemm2(const u16* __restrict__ Hh, const u16* __restrict__ Hl,
                                               const u16* __restrict__ W2ht, const u16* __restrict__ W2lt,
                                               const float* __restrict__ lng, const float* __restrict__ lnb,
                                               const float2* __restrict__ MU2,
                                               const float* __restrict__ b2,
                                               float* __restrict__ Z,
                                               u16* __restrict__ EXh, u16* __restrict__ EXl,
                                               float* __restrict__ SELF) {
  __shared__ float selfp[64][4];
  const int tid = threadIdx.x;
  const int lane = tid & 63, w = tid >> 6;
  const int wr = w >> 2, wc = w & 3;
  const int gm = blockIdx.x * 64;
  const int lr = lane & 15, kc2 = lane >> 4;

  // A rows owned by this lane: two 16-row fragments
  const int r0 = gm + wr * 32 + lr;
  const int r1 = r0 + 16;
  const float2 mu0 = MU2[r0], mu1 = MU2[r1];
  const u16* gh0 = Hh + ((size_t)r0 << 11) + kc2 * 8;
  const u16* gl0 = Hl + ((size_t)r0 << 11) + kc2 * 8;
  const u16* gh1 = Hh + ((size_t)r1 << 11) + kc2 * 8;
  const u16* gl1 = Hl + ((size_t)r1 << 11) + kc2 * 8;
  // B col base (wc*64 + lr), k chunk kc2
  const u16* gBh = W2ht + (((size_t)(wc * 64 + lr)) << 11) + kc2 * 8;
  const u16* gBl = W2lt + (((size_t)(wc * 64 + lr)) << 11) + kc2 * 8;

  f32x4 acc[2][4];
#pragma unroll
  for (int i = 0; i < 2; ++i)
#pragma unroll
    for (int j = 0; j < 4; ++j) acc[i][j] = (f32x4){0.f, 0.f, 0.f, 0.f};

  // in-register LN+ReLU+split of one 8-elem A chunk -> (ah, al)
  auto LN8 = [&](int kt, const uint4& hw, const uint4& lw, const float2& mu,
                 short8& ah, short8& al) {
    const int kb = kt * 32 + kc2 * 8;
    float4 g0 = *(const float4*)&lng[kb];
    float4 g1 = *(const float4*)&lng[kb + 4];
    float4 b0 = *(const float4*)&lnb[kb];
    float4 b1 = *(const float4*)&lnb[kb + 4];
    const float gg[8] = {g0.x, g0.y, g0.z, g0.w, g1.x, g1.y, g1.z, g1.w};
    const float bb[8] = {b0.x, b0.y, b0.z, b0.w, b1.x, b1.y, b1.z, b1.w};
    const unsigned hws[4] = {hw.x, hw.y, hw.z, hw.w};
    const unsigned lws[4] = {lw.x, lw.y, lw.z, lw.w};
#pragma unroll
    for (int p = 0; p < 4; ++p) {
#pragma unroll
      for (int e = 0; e < 2; ++e) {
        const int idx = 2 * p + e;
        const u16 hu = (u16)(hws[p] >> (16 * e));
        const u16 lu = (u16)(lws[p] >> (16 * e));
        const float h = bf2f(hu) + bf2f(lu);
        const float a1 = mu.y * gg[idx];
        const float y = fmaxf(fmaf(h, a1, bb[idx] - mu.x * a1), 0.f);
        const u16 yh = f2bf(y);
        const u16 yl = f2bf(y - bf2f(yh));
        ah[idx] = (short)yh;
        al[idx] = (short)yl;
      }
    }
  };

  auto STEP = [&](int kt, const uint4& h0, const uint4& l0,
                  const uint4& h1, const uint4& l1) {
    // B fragments direct from L2 (issued before LN so latency hides)
    short8 bh[4], bl[4];
#pragma unroll
    for (int j = 0; j < 4; ++j) {
      const size_t bo = ((size_t)(j * 16) << 11) + (size_t)kt * 32;
      bh[j] = *(const short8*)(gBh + bo);
      bl[j] = *(const short8*)(gBl + bo);
    }
    short8 ah0, al0, ah1, al1;
    LN8(kt, h0, l0, mu0, ah0, al0);
    LN8(kt, h1, l1, mu1, ah1, al1);
#pragma unroll
    for (int j = 0; j < 4; ++j) {
      acc[0][j] = __builtin_amdgcn_mfma_f32_16x16x32_bf16(ah0, bh[j], acc[0][j], 0, 0, 0);
      acc[0][j] = __builtin_amdgcn_mfma_f32_16x16x32_bf16(ah0, bl[j], acc[0][j], 0, 0, 0);
      acc[0][j] = __builtin_amdgcn_mfma_f32_16x16x32_bf16(al0, bh[j], acc[0][j], 0, 0, 0);
      acc[1][j] = __builtin_amdgcn_mfma_f32_16x16x32_bf16(ah1, bh[j], acc[1][j], 0, 0, 0);
      acc[1][j] = __builtin_amdgcn_mfma_f32_16x16x32_bf16(ah1, bl[j], acc[1][j], 0, 0, 0);
      acc[1][j] = __builtin_amdgcn_mfma_f32_16x16x32_bf16(al1, bh[j], acc[1][j], 0, 0, 0);
    }
  };

  // named even/odd A-register sets, prefetch depth 1, unroll x2
  uint4 cA_h0, cA_l0, cA_h1, cA_l1, nA_h0, nA_l0, nA_h1, nA_l1;
  cA_h0 = *(const uint4*)(gh0); cA_l0 = *(const uint4*)(gl0);
  cA_h1 = *(const uint4*)(gh1); cA_l1 = *(const uint4*)(gl1);

  for (int kt = 0; kt < 64; kt += 2) {
    // prefetch kt+1 (always valid: kt <= 62)
    nA_h0 = *(const uint4*)(gh0 + (kt + 1) * 32);
    nA_l0 = *(const uint4*)(gl0 + (kt + 1) * 32);
    nA_h1 = *(const uint4*)(gh1 + (kt + 1) * 32);
    nA_l1 = *(const uint4*)(gl1 + (kt + 1) * 32);
    STEP(kt, cA_h0, cA_l0, cA_h1, cA_l1);
    if (kt + 2 < 64) {
      cA_h0 = *(const uint4*)(gh0 + (kt + 2) * 32);
      cA_l0 = *(const uint4*)(gl0 + (kt + 2) * 32);
      cA_h1 = *(const uint4*)(gh1 + (kt + 2) * 32);
      cA_l1 = *(const uint4*)(gl1 + (kt + 2) * 32);
    }
    STEP(kt + 1, nA_h0, nA_l0, nA_h1, nA_l1);
  }

  // fused epilogue: bias + per-head (64-col == this wave's wc) LSE
  const int cc = lane & 15;
  float bias[4];
#pragma unroll
  for (int j = 0; j < 4; ++j) bias[j] = b2[wc * 64 + j * 16 + cc];

#pragma unroll
  for (int i = 0; i < 2; ++i)
#pragma unroll
    for (int reg = 0; reg < 4; ++reg) {
      const int rl = wr * 32 + i * 16 + ((lane >> 4) << 2) + reg;   // row in [0,64)
      const int row = gm + rl;
      float z[4];
#pragma unroll
      for (int j = 0; j < 4; ++j) z[j] = acc[i][j][reg] + bias[j];
      float mx = fmaxf(fmaxf(z[0], z[1]), fmaxf(z[2], z[3]));
#pragma unroll
      for (int m = 1; m <= 8; m <<= 1) mx = fmaxf(mx, __shfl_xor(mx, m));
      float se = expf(z[0] - mx) + expf(z[1] - mx) + expf(z[2] - mx) + expf(z[3] - mx);
#pragma unroll
      for (int m = 1; m <= 8; m <<= 1) se += __shfl_xor(se, m);
      const float lse = mx + logf(se);
      float selfc = 0.f;
#pragma unroll
      for (int j = 0; j < 4; ++j) {
        const float p = z[j] - lse;
        const float e = expf(p);
        selfc += e * p;
        const size_t o = (size_t)row * DD + wc * 64 + j * 16 + cc;
        Z[o] = z[j];
        u16 h = f2bf(e);
        EXh[o] = h;
        EXl[o] = f2bf(e - bf2f(h));
      }
#pragma unroll
      for (int m = 1; m <= 8; m <<= 1) selfc += __shfl_xor(selfc, m);
      if (cc == 0) selfp[rl][wc] = selfc;
    }
  __syncthreads();
  if (tid < 64)
    SELF[gm + tid] = selfp[tid][0] + selfp[tid][1] + selfp[tid][2] + selfp[tid][3];
}

// ---------------------------------------------------------------------------
// K4: logE = log(emb), 3-split bf16 (hi/mid/lo), layout [1024][256]
// ---------------------------------------------------------------------------
__global__ __launch_bounds__(256) void k_prep_le(const float* __restrict__ E,
                                                 u16* __restrict__ LEh, u16* __restrict__ LEm,
                                                 u16* __restrict__ LEl) {
  const size_t i = ((size_t)blockIdx.x * 256 + threadIdx.x) * 4;
  float4 v4 = *(const float4*)&E[i];
  float v[4] = {logf(v4.x), logf(v4.y), logf(v4.z), logf(v4.w)};
  u16 h[4], m_[4], l[4];
#pragma unroll
  for (int e = 0; e < 4; ++e) {
    h[e] = f2bf(v[e]);
    float r1 = v[e] - bf2f(h[e]);
    m_[e] = f2bf(r1);
    float r2 = r1 - bf2f(m_[e]);
    l[e] = f2bf(r2);
  }
  *(uint2*)&LEh[i] = make_uint2((unsigned)h[0] | ((unsigned)h[1] << 16), (unsigned)h[2] | ((unsigned)h[3] << 16));
  *(uint2*)&LEm[i] = make_uint2((unsigned)m_[0] | ((unsigned)m_[1] << 16), (unsigned)m_[2] | ((unsigned)m_[3] << 16));
  *(uint2*)&LEl[i] = make_uint2((unsigned)l[0] | ((unsigned)l[1] << 16), (unsigned)l[2] | ((unsigned)l[3] << 16));
}

// ---------------------------------------------------------------------------
// K5: dots = EX @ LE^T (5-term split MFMA) with FUSED per-tile argmax.
// 128x128 tile, single buffer, PV/PI [N][16].
// ---------------------------------------------------------------------------
__global__ __launch_bounds__(256) void k_dots(const u16* __restrict__ EXh, const u16* __restrict__ EXl,
                                              const u16* __restrict__ LEh, const u16* __restrict__ LEm,
                                              const u16* __restrict__ LEl,
                                              float* __restrict__ PV, int* __restrict__ PI) {
  __shared__ u16 sm[2560 * 8];
  const int tid = threadIdx.x;
  const int lane = tid & 63, w = tid >> 6;
  const int wr = w >> 1, wc = w & 1;
  const int gm = blockIdx.y * 128, m0 = blockIdx.x * 128;
  const int st_row = lane >> 2;
  const int st_k16 = (lane & 3) ^ ((lane >> 3) & 3);

  f32x4 acc[4][4];
#pragma unroll
  for (int i = 0; i < 4; ++i)
#pragma unroll
    for (int j = 0; j < 4; ++j) acc[i][j] = (f32x4){0.f, 0.f, 0.f, 0.f};

  const int rI = (lane & 15) * 4 + ((lane >> 4) ^ ((lane >> 1) & 3));
  for (int kt = 0; kt < 8; ++kt) {
    __syncthreads();
#pragma unroll
    for (int t = 0; t < 10; ++t) {
      const int f = w * 10 + t;
      const int mtx = f >> 3, tm = f & 7;
      const u16* src = (mtx == 0) ? EXh : (mtx == 1) ? EXl :
                       (mtx == 2) ? LEh : (mtx == 3) ? LEm : LEl;
      const int rowbase = (mtx < 2) ? gm : m0;
      const int row = rowbase + tm * 16 + st_row;
      const u16* g = src + ((size_t)row << 8) + (kt << 5) + st_k16 * 8;
      gload16(g, &sm[(f * 64 + lane) * 8]);
    }
    __syncthreads();
    short8 eh[4], el[4], bh[4], bm[4], bl[4];
#pragma unroll
    for (int i = 0; i < 4; ++i) {
      eh[i] = *(const short8*)(sm + ((wr * 4 + i) * 64 + rI) * 8);
      el[i] = *(const short8*)(sm + (512 + (wr * 4 + i) * 64 + rI) * 8);
      bh[i] = *(const short8*)(sm + (1024 + (wc * 4 + i) * 64 + rI) * 8);
      bm[i] = *(const short8*)(sm + (1536 + (wc * 4 + i) * 64 + rI) * 8);
      bl[i] = *(const short8*)(sm + (2048 + (wc * 4 + i) * 64 + rI) * 8);
    }
#pragma unroll
    for (int i = 0; i < 4; ++i)
#pragma unroll
      for (int j = 0; j < 4; ++j) {
        acc[i][j] = __builtin_amdgcn_mfma_f32_16x16x32_bf16(eh[i], bh[j], acc[i][j], 0, 0, 0);
        acc[i][j] = __builtin_amdgcn_mfma_f32_16x16x32_bf16(eh[i], bm[j], acc[i][j], 0, 0, 0);
        acc[i][j] = __builtin_amdgcn_mfma_f32_16x16x32_bf16(eh[i], bl[j], acc[i][j], 0, 0, 0);
        acc[i][j] = __builtin_amdgcn_mfma_f32_16x16x32_bf16(el[i], bh[j], acc[i][j], 0, 0, 0);
        acc[i][j] = __builtin_amdgcn_mfma_f32_16x16x32_bf16(el[i], bm[j], acc[i][j], 0, 0, 0);
      }
  }

  const int cc = lane & 15;
  const int mtile = blockIdx.x * 2 + wc;
#pragma unroll
  for (int i = 0; i < 4; ++i)
#pragma unroll
    for (int reg = 0; reg < 4; ++reg) {
      float bv = acc[i][0][reg];
      int bi = m0 + wc * 64 + cc;
#pragma unroll
      for (int j = 1; j < 4; ++j) {
        const float v = acc[i][j][reg];
        if (v > bv) { bv = v; bi = m0 + wc * 64 + j * 16 + cc; }
      }
#pragma unroll
      for (int msk = 8; msk; msk >>= 1) {
        const float ov = __shfl_xor(bv, msk);
        const int   oi = __shfl_xor(bi, msk);
        if (ov > bv || (ov == bv && oi < bi)) { bv = ov; bi = oi; }
      }
      if (cc == 0) {
        const int row = gm + wr * 64 + i * 16 + ((lane >> 4) << 2) + reg;
        PV[row * 16 + mtile] = bv;
        PI[row * 16 + mtile] = bi;
      }
    }
}

// ---------------------------------------------------------------------------
// K6: per row: reduce 16 partials, KL = self - best, gather Q. Wave per row.
// ---------------------------------------------------------------------------
__global__ __launch_bounds__(256) void k_scan(const float* __restrict__ PV,
                                              const int* __restrict__ PI,
                                              const float* __restrict__ SELF,
                                              const float* __restrict__ E,
                                              float* __restrict__ Q,
                                              float* __restrict__ KL) {
  const int tid = threadIdx.x;
  const int lane = tid & 63;
  const int row = blockIdx.x * 4 + (tid >> 6);

  float bv = -1e30f;
  int bi = 0x7fffffff;
  if (lane < 16) { bv = PV[row * 16 + lane]; bi = PI[row * 16 + lane]; }
#pragma unroll
  for (int m = 32; m; m >>= 1) {
    const float ov = __shfl_xor(bv, m);
    const int   oi = __shfl_xor(bi, m);
    if (ov > bv || (ov == bv && oi < bi)) { bv = ov; bi = oi; }
  }
  if (lane == 0) KL[row] = SELF[row] - bv;
  float4 e4 = *(const float4*)&E[((size_t)bi << 8) + lane * 4];
  *(float4*)&Q[((size_t)row << 8) + lane * 4] = e4;
}

// ---------------------------------------------------------------------------
// K7: loss = 0.25/B * sum_n kl[n]*mask[n]
// ---------------------------------------------------------------------------
__global__ __launch_bounds__(256) void k_loss(const float* __restrict__ KL,
                                              const float* __restrict__ MASK,
                                              float* __restrict__ out) {
  __shared__ float red[4];
  const int tid = threadIdx.x;
  float s = 0.f;
  for (int i = tid; i < NROWS; i += 256) s += KL[i] * MASK[i];
#pragma unroll
  for (int m = 32; m; m >>= 1) s += __shfl_xor(s, m);
  if ((tid & 63) == 0) red[tid >> 6] = s;
  __syncthreads();
  if (tid == 0) out[0] = (red[0] + red[1] + red[2] + red[3]) * (0.25f / 16.f);
}

// ---------------------------------------------------------------------------
extern "C" void kernel_launch(void* const* d_in, const int* in_sizes, int n_in,
                              void* d_out, int out_size, void* d_ws, size_t ws_size,
                              hipStream_t stream) {
  const float* x     = (const float*)d_in[0];
  const float* masks = (const float*)d_in[1];
  const float* W1    = (const float*)d_in[2];
  const float* ln_g  = (const float*)d_in[3];
  const float* ln_b  = (const float*)d_in[4];
  const float* W2    = (const float*)d_in[5];
  const float* b2    = (const float*)d_in[6];
  const float* emb   = (const float*)d_in[7];

  float* z_out = (float*)d_out;
  float* q_out = z_out + (size_t)NROWS * DD;
  float* loss_out = z_out + 2 * (size_t)NROWS * DD;

  char* ws = (char*)d_ws;
  u16*   Hh   = (u16*)(ws);                    //  67,108,864 (16384x2048)
  u16*   Hl   = (u16*)(ws + 67108864);         //  67,108,864
  u16*   W1ht = (u16*)(ws + 134217728);        //   2,097,152
  u16*   W1lt = (u16*)(ws + 136314880);        //   2,097,152
  u16*   W2ht = (u16*)(ws + 138412032);        //   1,048,576
  u16*   W2lt = (u16*)(ws + 139460608);        //   1,048,576
  u16*   LEh  = (u16*)(ws + 140509184);        //     524,288
  u16*   LEm  = (u16*)(ws + 141033472);        //     524,288
  u16*   LEl  = (u16*)(ws + 141557760);        //     524,288
  float* SELF = (float*)(ws + 142082048);      //      65,536
  float* KL   = (float*)(ws + 142147584);      //      65,536
  float2* MU2 = (float2*)(ws + 142213120);     //     131,072 -> end 142,344,192
  // overlays:
  float* PV   = (float*)(ws);                  //   1 MB (over Hh; H dead after gemm2)
  int*   PI   = (int*)(ws + 1048576);          //   1 MB
  float* STATS = (float*)q_out;                //   1 MB (q_out; dead before EX written)
  u16*   EXh  = (u16*)q_out;                   //   8 MB (after STATS consumed)
  u16*   EXl  = EXh + (size_t)NROWS * DD;      //   8 MB

  k_split_wT<<<dim3(64, 16), 256, 0, stream>>>(W1, W1ht, W1lt, INCH, CH);
  k_split_wT<<<dim3(8, 64), 256, 0, stream>>>(W2, W2ht, W2lt, CH, DD);
  k_prep_le<<<256, 256, 0, stream>>>(emb, LEh, LEm, LEl);

  k_gemm1<<<dim3(8, 64), 512, 0, stream>>>(x, W1ht, W1lt, Hh, Hl, STATS);
  k_rowstats<<<NROWS / 256, 256, 0, stream>>>(STATS, MU2);
  k_gemm2<<<NROWS / 64, 512, 0, stream>>>(Hh, Hl, W2ht, W2lt, ln_g, ln_b, MU2, b2,
                                          z_out, EXh, EXl, SELF);

  k_dots<<<dim3(8, 128), 256, 0, stream>>>(EXh, EXl, LEh, LEm, LEl, PV, PI);
  k_scan<<<4096, 256, 0, stream>>>(PV, PI, SELF, emb, q_out, KL);
  k_loss<<<1, 256, 0, stream>>>(KL, masks, loss_out);
}

// Round 13
// 319.791 us; speedup vs baseline: 1.3403x; 1.3403x over previous
//
#include <hip/hip_runtime.h>
#include <math.h>

#define NROWS 16384   // B*T
#define INCH  512
#define CH    2048
#define DD    256
#define MM    1024

typedef unsigned short u16;
typedef short short8 __attribute__((ext_vector_type(8)));
typedef float f32x4 __attribute__((ext_vector_type(4)));

__device__ __forceinline__ u16 f2bf(float f) {
  unsigned u = __float_as_uint(f);
  return (u16)((u + 0x7fffu + ((u >> 16) & 1u)) >> 16);
}
__device__ __forceinline__ float bf2f(u16 h) {
  return __uint_as_float(((unsigned)h) << 16);
}
__device__ __forceinline__ void gload16(const u16* g, u16* lds) {
  __builtin_amdgcn_global_load_lds((const __attribute__((address_space(1))) void*)g,
                                   (__attribute__((address_space(3))) void*)lds, 16, 0, 0);
}

// Coalesced-staging chunk mapping (16B chunks of 8 bf16 along K):
//   PC(row,kc) = (row>>4)*64 + (row&15)*4 + (kc ^ ((row>>1)&3))
//   frag read: chunk = group*64 + rI, rI = (lane&15)*4 + ((lane>>4)^((lane>>1)&3))

// src [R][C] fp32  ->  dh/dl [C][R] bf16 hi/lo   (transpose + split)
__global__ __launch_bounds__(256) void k_split_wT(const float* __restrict__ src,
                                                  u16* __restrict__ dh, u16* __restrict__ dl,
                                                  int R, int C) {
  __shared__ float t[32][33];
  const int tx = threadIdx.x & 31, ty = threadIdx.x >> 5;
  const int c0 = blockIdx.x * 32, r0 = blockIdx.y * 32;
#pragma unroll
  for (int i = 0; i < 4; ++i)
    t[ty + i * 8][tx] = src[(size_t)(r0 + ty + i * 8) * C + c0 + tx];
  __syncthreads();
#pragma unroll
  for (int i = 0; i < 4; ++i) {
    float v = t[tx][ty + i * 8];
    size_t o = (size_t)(c0 + ty + i * 8) * R + r0 + tx;
    u16 h = f2bf(v);
    dh[o] = h;
    dl[o] = f2bf(v - bf2f(h));
  }
}

// ---------------------------------------------------------------------------
// K1: H(split) = X @ W1.  Tile 256x256, BK=32, 512 thr (8 waves 2Mx4N),
// wave tile 128x64. XCD-swizzled 1-D grid (512): y=(hw&7)*8+hw/64,
// x=(hw>>3)&7 -> each XCD owns 8 consecutive row-tiles x all col-tiles,
// so X re-reads hit its private L2.
// ---------------------------------------------------------------------------
__global__ __launch_bounds__(512, 2) void k_gemm1(const float* __restrict__ X,
                                                  const u16* __restrict__ W1ht,
                                                  const u16* __restrict__ W1lt,
                                                  u16* __restrict__ Hh, u16* __restrict__ Hl,
                                                  float* __restrict__ STATS) {
  __shared__ u16 sm[2][4096 * 8];   // 128 KB
  const int tid = threadIdx.x;
  const int lane = tid & 63, w = tid >> 6;
  const int wr = w >> 2, wc = w & 3;
  const int hw = blockIdx.x;
  const int by = (hw & 7) * 8 + (hw >> 6);    // row-tile [0,64)
  const int bx = (hw >> 3) & 7;               // col-tile [0,8)
  const int gm = by * 256, n0 = bx * 256;

  const int arow = tid >> 1, ahalf = tid & 1;
  const float* gx = X + ((size_t)(gm + arow) << 9) + ahalf * 16;
  const int axor = (arow >> 1) & 3;
  const int pcbase = (arow >> 4) * 64 + (arow & 15) * 4;

  f32x4 acc[8][4];
#pragma unroll
  for (int i = 0; i < 8; ++i)
#pragma unroll
    for (int j = 0; j < 4; ++j) acc[i][j] = (f32x4){0.f, 0.f, 0.f, 0.f};

  float a16[16];
  auto A_LOAD = [&](int kt) {
    const float* p = gx + kt * 32;
    *(float4*)&a16[0]  = *(const float4*)(p);
    *(float4*)&a16[4]  = *(const float4*)(p + 4);
    *(float4*)&a16[8]  = *(const float4*)(p + 8);
    *(float4*)&a16[12] = *(const float4*)(p + 12);
  };
  auto A_WRITE = [&](int buf) {
#pragma unroll
    for (int g = 0; g < 2; ++g) {
      const int kc = ahalf * 2 + g;
      unsigned hw2[4], lw2[4];
#pragma unroll
      for (int p = 0; p < 4; ++p) {
        const float v0 = a16[g * 8 + 2 * p], v1 = a16[g * 8 + 2 * p + 1];
        const u16 h0 = f2bf(v0), h1 = f2bf(v1);
        const u16 l0 = f2bf(v0 - bf2f(h0)), l1 = f2bf(v1 - bf2f(h1));
        hw2[p] = (unsigned)h0 | ((unsigned)h1 << 16);
        lw2[p] = (unsigned)l0 | ((unsigned)l1 << 16);
      }
      const int pc = pcbase + (kc ^ axor);
      *(uint4*)&sm[buf][(size_t)pc * 8] = make_uint4(hw2[0], hw2[1], hw2[2], hw2[3]);
      *(uint4*)&sm[buf][(size_t)(1024 + pc) * 8] = make_uint4(lw2[0], lw2[1], lw2[2], lw2[3]);
    }
  };
  auto B_STAGE = [&](int buf, int kt) {
#pragma unroll
    for (int t = 0; t < 4; ++t) {
      const int f = t * 512 + tid;            // [0,2048)
      const int mtx = f >> 10;
      const int wi = f & 1023;
      const int grp = wi >> 6, s2 = wi & 63;
      const int srow = n0 + grp * 16 + (s2 >> 2);
      const int k16 = (s2 & 3) ^ ((s2 >> 3) & 3);
      const u16* src = mtx ? W1lt : W1ht;
      gload16(src + ((size_t)srow << 9) + (kt << 5) + k16 * 8,
              &sm[buf][(size_t)(2048 + f) * 8]);
    }
  };

  A_LOAD(0);
  B_STAGE(0, 0);
  A_WRITE(0);

  const int lr = lane & 15;
  const int rI = lr * 4 + ((lane >> 4) ^ ((lr >> 1) & 3));
  for (int kt = 0; kt < 16; ++kt) {
    __syncthreads();
    if (kt + 1 < 16) {
      A_LOAD(kt + 1);
      B_STAGE((kt + 1) & 1, kt + 1);
    }
    const u16* base = sm[kt & 1];
    short8 bh[4], bl[4];
#pragma unroll
    for (int j = 0; j < 4; ++j) {
      bh[j] = *(const short8*)(base + (size_t)(2048 + (wc * 4 + j) * 64 + rI) * 8);
      bl[j] = *(const short8*)(base + (size_t)(3072 + (wc * 4 + j) * 64 + rI) * 8);
    }
#pragma unroll
    for (int i = 0; i < 8; ++i) {
      short8 ah = *(const short8*)(base + (size_t)((wr * 8 + i) * 64 + rI) * 8);
      short8 al = *(const short8*)(base + (size_t)(1024 + (wr * 8 + i) * 64 + rI) * 8);
#pragma unroll
      for (int j = 0; j < 4; ++j) {
        acc[i][j] = __builtin_amdgcn_mfma_f32_16x16x32_bf16(ah, bh[j], acc[i][j], 0, 0, 0);
        acc[i][j] = __builtin_amdgcn_mfma_f32_16x16x32_bf16(ah, bl[j], acc[i][j], 0, 0, 0);
        acc[i][j] = __builtin_amdgcn_mfma_f32_16x16x32_bf16(al, bh[j], acc[i][j], 0, 0, 0);
      }
    }
    if (kt + 1 < 16) A_WRITE((kt + 1) & 1);
  }

  // ---- epilogue: 4 slabs of 64 rows via fp32 [64][260] + row stats ----
  float* smf = (float*)&sm[0][0];
  const int rr = (lane >> 4) << 2, cc = lane & 15;
  const int lrow = tid >> 3, c0 = (tid & 7) * 32;
#pragma unroll
  for (int s = 0; s < 4; ++s) {
    __syncthreads();
    if (wr == (s >> 1)) {
      const int ib = (s & 1) * 4;
#pragma unroll
      for (int ii = 0; ii < 4; ++ii)
#pragma unroll
        for (int j = 0; j < 4; ++j)
#pragma unroll
          for (int reg = 0; reg < 4; ++reg)
            smf[(ii * 16 + rr + reg) * 260 + wc * 64 + j * 16 + cc] = acc[ib + ii][j][reg];
    }
    __syncthreads();
    const int grow = gm + s * 64 + lrow;
    float s1 = 0.f, ss = 0.f;
#pragma unroll
    for (int q = 0; q < 4; ++q) {
      float v[8];
      *(f32x4*)&v[0] = *(const f32x4*)&smf[lrow * 260 + c0 + q * 8];
      *(f32x4*)&v[4] = *(const f32x4*)&smf[lrow * 260 + c0 + q * 8 + 4];
#pragma unroll
      for (int e = 0; e < 8; ++e) { s1 += v[e]; ss += v[e] * v[e]; }
      unsigned hw2[4], lw2[4];
#pragma unroll
      for (int p = 0; p < 4; ++p) {
        const u16 h0 = f2bf(v[2 * p]), h1 = f2bf(v[2 * p + 1]);
        const u16 l0 = f2bf(v[2 * p] - bf2f(h0)), l1 = f2bf(v[2 * p + 1] - bf2f(h1));
        hw2[p] = (unsigned)h0 | ((unsigned)h1 << 16);
        lw2[p] = (unsigned)l0 | ((unsigned)l1 << 16);
      }
      const size_t o = (size_t)grow * CH + n0 + c0 + q * 8;
      *(uint4*)&Hh[o] = make_uint4(hw2[0], hw2[1], hw2[2], hw2[3]);
      *(uint4*)&Hl[o] = make_uint4(lw2[0], lw2[1], lw2[2], lw2[3]);
    }
#pragma unroll
    for (int m = 1; m <= 4; m <<= 1) { s1 += __shfl_xor(s1, m); ss += __shfl_xor(ss, m); }
    if ((tid & 7) == 0)
      *(float2*)&STATS[(size_t)grow * 16 + bx * 2] = make_float2(s1, ss);
  }
}

// ---------------------------------------------------------------------------
// K2: reduce 8 slice-partials per row -> (mu, rinv)
// ---------------------------------------------------------------------------
__global__ __launch_bounds__(256) void k_rowstats(const float* __restrict__ STATS,
                                                  float2* __restrict__ MU2) {
  const int row = blockIdx.x * 256 + threadIdx.x;
  float s = 0.f, ss = 0.f;
#pragma unroll
  for (int i = 0; i < 8; ++i) {
    float2 p = *(const float2*)&STATS[((size_t)row << 4) + i * 2];
    s += p.x; ss += p.y;
  }
  const float mu = s * (1.f / CH);
  const float var = ss * (1.f / CH) - mu * mu;
  MU2[row] = make_float2(mu, 1.f / sqrtf(var + 1e-5f));
}

// ---------------------------------------------------------------------------
// K3: fused Z = relu(LN(H)) @ W2 + b2 -> per-head LSE -> Z, EXh/EXl, SELF.
// R9 structure (proven 110us): BM=64, BN=256, BK=32, 512 thr, 80KB dbuf LDS,
// 2-deep A register pipeline, A via global->reg->LN->split->ds_write
// (waves 0-3), B via global_load_lds (waves 4-7).
// ---------------------------------------------------------------------------
__global__ __launch_bounds__(512) void k_gemm2(const u16* __restrict__ Hh, const u16* __restrict__ Hl,
                                               const u16* __restrict__ W2ht, const u16* __restrict__ W2lt,
                                               const float* __restrict__ lng, const float* __restrict__ lnb,
                                               const float2* __restrict__ MU2,
                                               const float* __restrict__ b2,
                                               float* __restrict__ Z,
                                               u16* __restrict__ EXh, u16* __restrict__ EXl,
                                               float* __restrict__ SELF) {
  __shared__ u16 sm[2][2560 * 8];   // 80 KB
  __shared__ float selfp[64][4];
  const int tid = threadIdx.x;
  const int lane = tid & 63, w = tid >> 6;
  const int wr = w >> 2, wc = w & 3;
  const int gm = blockIdx.x * 64;
  const int st_row = lane >> 2;
  const int st_k16 = (lane & 3) ^ ((lane >> 3) & 3);

  const int arow = tid >> 2, akc = tid & 3;
  const int pcA = (arow >> 4) * 64 + (arow & 15) * 4 + (akc ^ ((arow >> 1) & 3));
  float2 murv = make_float2(0.f, 0.f);
  const u16 *gHh = nullptr, *gHl = nullptr;
  if (tid < 256) {
    murv = MU2[gm + arow];
    gHh = Hh + ((size_t)(gm + arow) << 11) + akc * 8;
    gHl = Hl + ((size_t)(gm + arow) << 11) + akc * 8;
  }

  f32x4 acc[2][4];
#pragma unroll
  for (int i = 0; i < 2; ++i)
#pragma unroll
    for (int j = 0; j < 4; ++j) acc[i][j] = (f32x4){0.f, 0.f, 0.f, 0.f};

  uint4 hwA, lwA, hwB, lwB;
  auto A_LOAD_A = [&](int kt) {
    if (tid < 256) { hwA = *(const uint4*)(gHh + kt * 32); lwA = *(const uint4*)(gHl + kt * 32); }
  };
  auto A_LOAD_B = [&](int kt) {
    if (tid < 256) { hwB = *(const uint4*)(gHh + kt * 32); lwB = *(const uint4*)(gHl + kt * 32); }
  };
  auto B_STAGE = [&](int buf, int kt) {
    if (w >= 4) {
#pragma unroll
      for (int t = 0; t < 8; ++t) {
        const int f = (w - 4) * 8 + t;
        const int g = (f < 16) ? f : f - 16;
        const u16* src = (f < 16) ? W2ht : W2lt;
        const int slot = ((f < 16) ? 512 + f * 64 : 1536 + (f - 16) * 64) + lane;
        const int row = g * 16 + st_row;
        gload16(src + ((size_t)row << 11) + (kt << 5) + st_k16 * 8,
                &sm[buf][(size_t)slot * 8]);
      }
    }
  };
  auto LN_WRITE = [&](int buf, int kt, const uint4& hwreg, const uint4& lwreg) {
    if (tid < 256) {
      const int kb = kt * 32 + akc * 8;
      float4 g0 = *(const float4*)&lng[kb];
      float4 g1 = *(const float4*)&lng[kb + 4];
      float4 bb0 = *(const float4*)&lnb[kb];
      float4 bb1 = *(const float4*)&lnb[kb + 4];
      const float gg[8] = {g0.x, g0.y, g0.z, g0.w, g1.x, g1.y, g1.z, g1.w};
      const float bb[8] = {bb0.x, bb0.y, bb0.z, bb0.w, bb1.x, bb1.y, bb1.z, bb1.w};
      const unsigned hws[4] = {hwreg.x, hwreg.y, hwreg.z, hwreg.w};
      const unsigned lws[4] = {lwreg.x, lwreg.y, lwreg.z, lwreg.w};
      unsigned oh[4], ol[4];
#pragma unroll
      for (int p = 0; p < 4; ++p) {
        u16 yh[2], yl[2];
#pragma unroll
        for (int e = 0; e < 2; ++e) {
          const u16 hu = (u16)(hws[p] >> (16 * e));
          const u16 lu = (u16)(lws[p] >> (16 * e));
          const float h = bf2f(hu) + bf2f(lu);
          const float a1 = murv.y * gg[2 * p + e];
          const float y = fmaxf(fmaf(h, a1, bb[2 * p + e] - murv.x * a1), 0.f);
          yh[e] = f2bf(y);
          yl[e] = f2bf(y - bf2f(yh[e]));
        }
        oh[p] = (unsigned)yh[0] | ((unsigned)yh[1] << 16);
        ol[p] = (unsigned)yl[0] | ((unsigned)yl[1] << 16);
      }
      *(uint4*)&sm[buf][(size_t)pcA * 8] = make_uint4(oh[0], oh[1], oh[2], oh[3]);
      *(uint4*)&sm[buf][(size_t)(256 + pcA) * 8] = make_uint4(ol[0], ol[1], ol[2], ol[3]);
    }
  };

  const int lr = lane & 15;
  const int rI = lr * 4 + ((lane >> 4) ^ ((lr >> 1) & 3));

  auto MFMA_STEP = [&](const u16* base) {
    short8 ah[2], al[2], bh[4], bl[4];
#pragma unroll
    for (int i = 0; i < 2; ++i) {
      ah[i] = *(const short8*)(base + ((wr * 2 + i) * 64 + rI) * 8);
      al[i] = *(const short8*)(base + (256 + (wr * 2 + i) * 64 + rI) * 8);
    }
#pragma unroll
    for (int j = 0; j < 4; ++j) {
      bh[j] = *(const short8*)(base + (512 + (wc * 4 + j) * 64 + rI) * 8);
      bl[j] = *(const short8*)(base + (1536 + (wc * 4 + j) * 64 + rI) * 8);
    }
#pragma unroll
    for (int i = 0; i < 2; ++i)
#pragma unroll
      for (int j = 0; j < 4; ++j) {
        acc[i][j] = __builtin_amdgcn_mfma_f32_16x16x32_bf16(ah[i], bh[j], acc[i][j], 0, 0, 0);
        acc[i][j] = __builtin_amdgcn_mfma_f32_16x16x32_bf16(ah[i], bl[j], acc[i][j], 0, 0, 0);
        acc[i][j] = __builtin_amdgcn_mfma_f32_16x16x32_bf16(al[i], bh[j], acc[i][j], 0, 0, 0);
      }
  };

  A_LOAD_A(0);
  B_STAGE(0, 0);
  LN_WRITE(0, 0, hwA, lwA);
  A_LOAD_B(1);

  for (int kt = 0; kt < 64; kt += 2) {
    __syncthreads();
    if (kt + 2 < 64) A_LOAD_A(kt + 2);
    B_STAGE(1, kt + 1);
    MFMA_STEP(sm[0]);
    LN_WRITE(1, kt + 1, hwB, lwB);
    __syncthreads();
    if (kt + 3 < 64) A_LOAD_B(kt + 3);
    if (kt + 2 < 64) B_STAGE(0, kt + 2);
    MFMA_STEP(sm[1]);
    if (kt + 2 < 64) LN_WRITE(0, kt + 2, hwA, lwA);
  }

  const int cc = lane & 15;
  float bias[4];
#pragma unroll
  for (int j = 0; j < 4; ++j) bias[j] = b2[wc * 64 + j * 16 + cc];

#pragma unroll
  for (int i = 0; i < 2; ++i)
#pragma unroll
    for (int reg = 0; reg < 4; ++reg) {
      const int rl = wr * 32 + i * 16 + ((lane >> 4) << 2) + reg;
      const int row = gm + rl;
      float z[4];
#pragma unroll
      for (int j = 0; j < 4; ++j) z[j] = acc[i][j][reg] + bias[j];
      float mx = fmaxf(fmaxf(z[0], z[1]), fmaxf(z[2], z[3]));
#pragma unroll
      for (int m = 1; m <= 8; m <<= 1) mx = fmaxf(mx, __shfl_xor(mx, m));
      float se = expf(z[0] - mx) + expf(z[1] - mx) + expf(z[2] - mx) + expf(z[3] - mx);
#pragma unroll
      for (int m = 1; m <= 8; m <<= 1) se += __shfl_xor(se, m);
      const float lse = mx + logf(se);
      float selfc = 0.f;
#pragma unroll
      for (int j = 0; j < 4; ++j) {
        const float p = z[j] - lse;
        const float e = expf(p);
        selfc += e * p;
        const size_t o = (size_t)row * DD + wc * 64 + j * 16 + cc;
        Z[o] = z[j];
        u16 h = f2bf(e);
        EXh[o] = h;
        EXl[o] = f2bf(e - bf2f(h));
      }
#pragma unroll
      for (int m = 1; m <= 8; m <<= 1) selfc += __shfl_xor(selfc, m);
      if (cc == 0) selfp[rl][wc] = selfc;
    }
  __syncthreads();
  if (tid < 64)
    SELF[gm + tid] = selfp[tid][0] + selfp[tid][1] + selfp[tid][2] + selfp[tid][3];
}

// ---------------------------------------------------------------------------
// K4: logE = log(emb), 3-split bf16 (hi/mid/lo), layout [1024][256]
// ---------------------------------------------------------------------------
__global__ __launch_bounds__(256) void k_prep_le(const float* __restrict__ E,
                                                 u16* __restrict__ LEh, u16* __restrict__ LEm,
                                                 u16* __restrict__ LEl) {
  const size_t i = ((size_t)blockIdx.x * 256 + threadIdx.x) * 4;
  float4 v4 = *(const float4*)&E[i];
  float v[4] = {logf(v4.x), logf(v4.y), logf(v4.z), logf(v4.w)};
  u16 h[4], m_[4], l[4];
#pragma unroll
  for (int e = 0; e < 4; ++e) {
    h[e] = f2bf(v[e]);
    float r1 = v[e] - bf2f(h[e]);
    m_[e] = f2bf(r1);
    float r2 = r1 - bf2f(m_[e]);
    l[e] = f2bf(r2);
  }
  *(uint2*)&LEh[i] = make_uint2((unsigned)h[0] | ((unsigned)h[1] << 16), (unsigned)h[2] | ((unsigned)h[3] << 16));
  *(uint2*)&LEm[i] = make_uint2((unsigned)m_[0] | ((unsigned)m_[1] << 16), (unsigned)m_[2] | ((unsigned)m_[3] << 16));
  *(uint2*)&LEl[i] = make_uint2((unsigned)l[0] | ((unsigned)l[1] << 16), (unsigned)l[2] | ((unsigned)l[3] << 16));
}

// ---------------------------------------------------------------------------
// K5: dots = EX @ LE^T (5-term split MFMA) with FUSED per-tile argmax.
// 128x128 tile, single buffer, PV/PI [N][16]. XCD-swizzled 1-D grid (1024):
// y=(hw&7)*16+hw/64, x=(hw>>3)&7 -> per-XCD working set EX 2MB + LE 1.5MB <= L2.
// ---------------------------------------------------------------------------
__global__ __launch_bounds__(256) void k_dots(const u16* __restrict__ EXh, const u16* __restrict__ EXl,
                                              const u16* __restrict__ LEh, const u16* __restrict__ LEm,
                                              const u16* __restrict__ LEl,
                                              float* __restrict__ PV, int* __restrict__ PI) {
  __shared__ u16 sm[2560 * 8];
  const int tid = threadIdx.x;
  const int lane = tid & 63, w = tid >> 6;
  const int wr = w >> 1, wc = w & 1;
  const int hw = blockIdx.x;
  const int by = (hw & 7) * 16 + (hw >> 6);   // row-tile [0,128)
  const int bx = (hw >> 3) & 7;               // m-tile [0,8)
  const int gm = by * 128, m0 = bx * 128;
  const int st_row = lane >> 2;
  const int st_k16 = (lane & 3) ^ ((lane >> 3) & 3);

  f32x4 acc[4][4];
#pragma unroll
  for (int i = 0; i < 4; ++i)
#pragma unroll
    for (int j = 0; j < 4; ++j) acc[i][j] = (f32x4){0.f, 0.f, 0.f, 0.f};

  const int rI = (lane & 15) * 4 + ((lane >> 4) ^ ((lane >> 1) & 3));
  for (int kt = 0; kt < 8; ++kt) {
    __syncthreads();
#pragma unroll
    for (int t = 0; t < 10; ++t) {
      const int f = w * 10 + t;
      const int mtx = f >> 3, tm = f & 7;
      const u16* src = (mtx == 0) ? EXh : (mtx == 1) ? EXl :
                       (mtx == 2) ? LEh : (mtx == 3) ? LEm : LEl;
      const int rowbase = (mtx < 2) ? gm : m0;
      const int row = rowbase + tm * 16 + st_row;
      const u16* g = src + ((size_t)row << 8) + (kt << 5) + st_k16 * 8;
      gload16(g, &sm[(f * 64 + lane) * 8]);
    }
    __syncthreads();
    short8 eh[4], el[4], bh[4], bm[4], bl[4];
#pragma unroll
    for (int i = 0; i < 4; ++i) {
      eh[i] = *(const short8*)(sm + ((wr * 4 + i) * 64 + rI) * 8);
      el[i] = *(const short8*)(sm + (512 + (wr * 4 + i) * 64 + rI) * 8);
      bh[i] = *(const short8*)(sm + (1024 + (wc * 4 + i) * 64 + rI) * 8);
      bm[i] = *(const short8*)(sm + (1536 + (wc * 4 + i) * 64 + rI) * 8);
      bl[i] = *(const short8*)(sm + (2048 + (wc * 4 + i) * 64 + rI) * 8);
    }
#pragma unroll
    for (int i = 0; i < 4; ++i)
#pragma unroll
      for (int j = 0; j < 4; ++j) {
        acc[i][j] = __builtin_amdgcn_mfma_f32_16x16x32_bf16(eh[i], bh[j], acc[i][j], 0, 0, 0);
        acc[i][j] = __builtin_amdgcn_mfma_f32_16x16x32_bf16(eh[i], bm[j], acc[i][j], 0, 0, 0);
        acc[i][j] = __builtin_amdgcn_mfma_f32_16x16x32_bf16(eh[i], bl[j], acc[i][j], 0, 0, 0);
        acc[i][j] = __builtin_amdgcn_mfma_f32_16x16x32_bf16(el[i], bh[j], acc[i][j], 0, 0, 0);
        acc[i][j] = __builtin_amdgcn_mfma_f32_16x16x32_bf16(el[i], bm[j], acc[i][j], 0, 0, 0);
      }
  }

  const int cc = lane & 15;
  const int mtile = bx * 2 + wc;
#pragma unroll
  for (int i = 0; i < 4; ++i)
#pragma unroll
    for (int reg = 0; reg < 4; ++reg) {
      float bv = acc[i][0][reg];
      int bi = m0 + wc * 64 + cc;
#pragma unroll
      for (int j = 1; j < 4; ++j) {
        const float v = acc[i][j][reg];
        if (v > bv) { bv = v; bi = m0 + wc * 64 + j * 16 + cc; }
      }
#pragma unroll
      for (int msk = 8; msk; msk >>= 1) {
        const float ov = __shfl_xor(bv, msk);
        const int   oi = __shfl_xor(bi, msk);
        if (ov > bv || (ov == bv && oi < bi)) { bv = ov; bi = oi; }
      }
      if (cc == 0) {
        const int row = gm + wr * 64 + i * 16 + ((lane >> 4) << 2) + reg;
        PV[row * 16 + mtile] = bv;
        PI[row * 16 + mtile] = bi;
      }
    }
}

// ---------------------------------------------------------------------------
// K6: per row: reduce 16 partials, KL = self - best, gather Q. Wave per row.
// ---------------------------------------------------------------------------
__global__ __launch_bounds__(256) void k_scan(const float* __restrict__ PV,
                                              const int* __restrict__ PI,
                                              const float* __restrict__ SELF,
                                              const float* __restrict__ E,
                                              float* __restrict__ Q,
                                              float* __restrict__ KL) {
  const int tid = threadIdx.x;
  const int lane = tid & 63;
  const int row = blockIdx.x * 4 + (tid >> 6);

  float bv = -1e30f;
  int bi = 0x7fffffff;
  if (lane < 16) { bv = PV[row * 16 + lane]; bi = PI[row * 16 + lane]; }
#pragma unroll
  for (int m = 32; m; m >>= 1) {
    const float ov = __shfl_xor(bv, m);
    const int   oi = __shfl_xor(bi, m);
    if (ov > bv || (ov == bv && oi < bi)) { bv = ov; bi = oi; }
  }
  if (lane == 0) KL[row] = SELF[row] - bv;
  float4 e4 = *(const float4*)&E[((size_t)bi << 8) + lane * 4];
  *(float4*)&Q[((size_t)row << 8) + lane * 4] = e4;
}

// ---------------------------------------------------------------------------
// K7: loss = 0.25/B * sum_n kl[n]*mask[n]
// ---------------------------------------------------------------------------
__global__ __launch_bounds__(256) void k_loss(const float* __restrict__ KL,
                                              const float* __restrict__ MASK,
                                              float* __restrict__ out) {
  __shared__ float red[4];
  const int tid = threadIdx.x;
  float s = 0.f;
  for (int i = tid; i < NROWS; i += 256) s += KL[i] * MASK[i];
#pragma unroll
  for (int m = 32; m; m >>= 1) s += __shfl_xor(s, m);
  if ((tid & 63) == 0) red[tid >> 6] = s;
  __syncthreads();
  if (tid == 0) out[0] = (red[0] + red[1] + red[2] + red[3]) * (0.25f / 16.f);
}

// ---------------------------------------------------------------------------
extern "C" void kernel_launch(void* const* d_in, const int* in_sizes, int n_in,
                              void* d_out, int out_size, void* d_ws, size_t ws_size,
                              hipStream_t stream) {
  const float* x     = (const float*)d_in[0];
  const float* masks = (const float*)d_in[1];
  const float* W1    = (const float*)d_in[2];
  const float* ln_g  = (const float*)d_in[3];
  const float* ln_b  = (const float*)d_in[4];
  const float* W2    = (const float*)d_in[5];
  const float* b2    = (const float*)d_in[6];
  const float* emb   = (const float*)d_in[7];

  float* z_out = (float*)d_out;
  float* q_out = z_out + (size_t)NROWS * DD;
  float* loss_out = z_out + 2 * (size_t)NROWS * DD;

  char* ws = (char*)d_ws;
  u16*   Hh   = (u16*)(ws);                    //  67,108,864 (16384x2048)
  u16*   Hl   = (u16*)(ws + 67108864);         //  67,108,864
  u16*   W1ht = (u16*)(ws + 134217728);        //   2,097,152
  u16*   W1lt = (u16*)(ws + 136314880);        //   2,097,152
  u16*   W2ht = (u16*)(ws + 138412032);        //   1,048,576
  u16*   W2lt = (u16*)(ws + 139460608);        //   1,048,576
  u16*   LEh  = (u16*)(ws + 140509184);        //     524,288
  u16*   LEm  = (u16*)(ws + 141033472);        //     524,288
  u16*   LEl  = (u16*)(ws + 141557760);        //     524,288
  float* SELF = (float*)(ws + 142082048);      //      65,536
  float* KL   = (float*)(ws + 142147584);      //      65,536
  float2* MU2 = (float2*)(ws + 142213120);     //     131,072 -> end 142,344,192
  // overlays:
  float* PV   = (float*)(ws);                  //   1 MB (over Hh; H dead after gemm2)
  int*   PI   = (int*)(ws + 1048576);          //   1 MB
  float* STATS = (float*)q_out;                //   1 MB (q_out; dead before EX written)
  u16*   EXh  = (u16*)q_out;                   //   8 MB (after STATS consumed)
  u16*   EXl  = EXh + (size_t)NROWS * DD;      //   8 MB

  k_split_wT<<<dim3(64, 16), 256, 0, stream>>>(W1, W1ht, W1lt, INCH, CH);
  k_split_wT<<<dim3(8, 64), 256, 0, stream>>>(W2, W2ht, W2lt, CH, DD);
  k_prep_le<<<256, 256, 0, stream>>>(emb, LEh, LEm, LEl);

  k_gemm1<<<512, 512, 0, stream>>>(x, W1ht, W1lt, Hh, Hl, STATS);
  k_rowstats<<<NROWS / 256, 256, 0, stream>>>(STATS, MU2);
  k_gemm2<<<NROWS / 64, 512, 0, stream>>>(Hh, Hl, W2ht, W2lt, ln_g, ln_b, MU2, b2,
                                          z_out, EXh, EXl, SELF);

  k_dots<<<1024, 256, 0, stream>>>(EXh, EXl, LEh, LEm, LEl, PV, PI);
  k_scan<<<4096, 256, 0, stream>>>(PV, PI, SELF, emb, q_out, KL);
  k_loss<<<1, 256, 0, stream>>>(KL, masks, loss_out);
}

// Round 14
// 200.984 us; speedup vs baseline: 2.1326x; 1.5911x over previous
//
#include <hip/hip_runtime.h>
#include <math.h>

#define NROWS 16384   // B*T
#define INCH  512
#define CH    2048
#define DD    256
#define MM    1024

typedef unsigned short u16;
typedef short short8 __attribute__((ext_vector_type(8)));
typedef float f32x4 __attribute__((ext_vector_type(4)));

__device__ __forceinline__ u16 f2bf(float f) {
  unsigned u = __float_as_uint(f);
  return (u16)((u + 0x7fffu + ((u >> 16) & 1u)) >> 16);
}
__device__ __forceinline__ float bf2f(u16 h) {
  return __uint_as_float(((unsigned)h) << 16);
}
__device__ __forceinline__ void gload16(const u16* g, u16* lds) {
  __builtin_amdgcn_global_load_lds((const __attribute__((address_space(1))) void*)g,
                                   (__attribute__((address_space(3))) void*)lds, 16, 0, 0);
}

// Coalesced-staging chunk mapping (16B chunks of 8 bf16 along K):
//   PC(row,kc) = (row>>4)*64 + (row&15)*4 + (kc ^ ((row>>1)&3))
//   frag read: chunk = group*64 + rI, rI = (lane&15)*4 + ((lane>>4)^((lane>>1)&3))

// src [R][C] fp32  ->  d [C][R] bf16 (transpose + round)
__global__ __launch_bounds__(256) void k_split_wT(const float* __restrict__ src,
                                                  u16* __restrict__ dh, int R, int C) {
  __shared__ float t[32][33];
  const int tx = threadIdx.x & 31, ty = threadIdx.x >> 5;
  const int c0 = blockIdx.x * 32, r0 = blockIdx.y * 32;
#pragma unroll
  for (int i = 0; i < 4; ++i)
    t[ty + i * 8][tx] = src[(size_t)(r0 + ty + i * 8) * C + c0 + tx];
  __syncthreads();
#pragma unroll
  for (int i = 0; i < 4; ++i) {
    float v = t[tx][ty + i * 8];
    dh[(size_t)(c0 + ty + i * 8) * R + r0 + tx] = f2bf(v);
  }
}

// ---------------------------------------------------------------------------
// K1: H = bf16(X @ W1).  m97 structure: 128x128 tile, BK=32, 4 waves (2x2),
// 32KB dbuf LDS -> multiple blocks/CU. A: fp32 global->reg->bf16->ds_write.
// B: bf16 W1^T via global_load_lds. XCD-swizzled grid (2048 blocks):
// xcd=hw&7, u=hw>>3: y = xcd*16 + (u>>4), x = u&15 (bijective).
// Epilogue: 4 slabs of 32 rows via fp32 [32][132] + row stats per 128-slice.
// ---------------------------------------------------------------------------
__global__ __launch_bounds__(256) void k_gemm1(const float* __restrict__ X,
                                               const u16* __restrict__ W1ht,
                                               u16* __restrict__ Hh,
                                               float* __restrict__ STATS) {
  __shared__ u16 sm[2][1024 * 8];   // 32 KB
  const int tid = threadIdx.x;
  const int lane = tid & 63, w = tid >> 6;
  const int wr = w >> 1, wc = w & 1;
  const int hw = blockIdx.x;
  const int u = hw >> 3;
  const int by = (hw & 7) * 16 + (u >> 4);   // [0,128)
  const int bx = u & 15;                     // [0,16)
  const int gm = by * 128, n0 = bx * 128;

  // A staging site: row arow (0..127), half ahalf (16 k-elems each)
  const int arow = tid >> 1, ahalf = tid & 1;
  const float* gx = X + ((size_t)(gm + arow) << 9) + ahalf * 16;
  const int axor = (arow >> 1) & 3;
  const int pcbase = (arow >> 4) * 64 + (arow & 15) * 4;

  f32x4 acc[4][4];
#pragma unroll
  for (int i = 0; i < 4; ++i)
#pragma unroll
    for (int j = 0; j < 4; ++j) acc[i][j] = (f32x4){0.f, 0.f, 0.f, 0.f};

  float a16[16];
  auto A_LOAD = [&](int kt) {
    const float* p = gx + kt * 32;
    *(float4*)&a16[0]  = *(const float4*)(p);
    *(float4*)&a16[4]  = *(const float4*)(p + 4);
    *(float4*)&a16[8]  = *(const float4*)(p + 8);
    *(float4*)&a16[12] = *(const float4*)(p + 12);
  };
  auto A_WRITE = [&](int buf) {
#pragma unroll
    for (int g = 0; g < 2; ++g) {
      const int kc = ahalf * 2 + g;
      unsigned hw2[4];
#pragma unroll
      for (int p = 0; p < 4; ++p) {
        const u16 h0 = f2bf(a16[g * 8 + 2 * p]);
        const u16 h1 = f2bf(a16[g * 8 + 2 * p + 1]);
        hw2[p] = (unsigned)h0 | ((unsigned)h1 << 16);
      }
      const int pc = pcbase + (kc ^ axor);
      *(uint4*)&sm[buf][(size_t)pc * 8] = make_uint4(hw2[0], hw2[1], hw2[2], hw2[3]);
    }
  };
  auto B_STAGE = [&](int buf, int kt) {
#pragma unroll
    for (int t = 0; t < 2; ++t) {
      const int f = t * 256 + tid;            // [0,512)
      const int grp = f >> 6, s2 = f & 63;
      const int srow = n0 + grp * 16 + (s2 >> 2);
      const int k16 = (s2 & 3) ^ ((s2 >> 3) & 3);
      gload16(W1ht + ((size_t)srow << 9) + (kt << 5) + k16 * 8,
              &sm[buf][(size_t)(512 + f) * 8]);
    }
  };

  A_LOAD(0);
  B_STAGE(0, 0);
  A_WRITE(0);

  const int lr = lane & 15;
  const int rI = lr * 4 + ((lane >> 4) ^ ((lr >> 1) & 3));
  for (int kt = 0; kt < 16; ++kt) {
    __syncthreads();
    if (kt + 1 < 16) {
      A_LOAD(kt + 1);
      B_STAGE((kt + 1) & 1, kt + 1);
    }
    const u16* base = sm[kt & 1];
    short8 bh[4];
#pragma unroll
    for (int j = 0; j < 4; ++j)
      bh[j] = *(const short8*)(base + (size_t)(512 + (wc * 4 + j) * 64 + rI) * 8);
#pragma unroll
    for (int i = 0; i < 4; ++i) {
      short8 ah = *(const short8*)(base + (size_t)((wr * 4 + i) * 64 + rI) * 8);
#pragma unroll
      for (int j = 0; j < 4; ++j)
        acc[i][j] = __builtin_amdgcn_mfma_f32_16x16x32_bf16(ah, bh[j], acc[i][j], 0, 0, 0);
    }
    if (kt + 1 < 16) A_WRITE((kt + 1) & 1);
  }

  // ---- epilogue: 4 slabs of 32 rows via fp32 [32][132] + row stats ----
  float* smf = (float*)&sm[0][0];
  const int rr = (lane >> 4) << 2, cc = lane & 15;
  const int lrow = tid >> 3, cg = tid & 7;
#pragma unroll
  for (int s = 0; s < 4; ++s) {
    __syncthreads();
    if (wr == (s >> 1)) {
#pragma unroll
      for (int ii = 0; ii < 2; ++ii) {
        const int i = (s & 1) * 2 + ii;
#pragma unroll
        for (int j = 0; j < 4; ++j)
#pragma unroll
          for (int reg = 0; reg < 4; ++reg)
            smf[(ii * 16 + rr + reg) * 132 + wc * 64 + j * 16 + cc] = acc[i][j][reg];
      }
    }
    __syncthreads();
    const int grow = gm + s * 32 + lrow;
    float s1 = 0.f, ss = 0.f;
    float v[16];
#pragma unroll
    for (int q = 0; q < 4; ++q)
      *(f32x4*)&v[q * 4] = *(const f32x4*)&smf[lrow * 132 + cg * 16 + q * 4];
#pragma unroll
    for (int e = 0; e < 16; ++e) { s1 += v[e]; ss += v[e] * v[e]; }
    unsigned hw2[8];
#pragma unroll
    for (int p = 0; p < 8; ++p) {
      const u16 h0 = f2bf(v[2 * p]), h1 = f2bf(v[2 * p + 1]);
      hw2[p] = (unsigned)h0 | ((unsigned)h1 << 16);
    }
    const size_t o = (size_t)grow * CH + n0 + cg * 16;
    *(uint4*)&Hh[o] = make_uint4(hw2[0], hw2[1], hw2[2], hw2[3]);
    *(uint4*)&Hh[o + 8] = make_uint4(hw2[4], hw2[5], hw2[6], hw2[7]);
#pragma unroll
    for (int m = 1; m <= 4; m <<= 1) { s1 += __shfl_xor(s1, m); ss += __shfl_xor(ss, m); }
    if (cg == 0)
      *(float2*)&STATS[(size_t)grow * 32 + bx * 2] = make_float2(s1, ss);
  }
}

// ---------------------------------------------------------------------------
// K2: reduce 16 slice-partials per row -> (mu, rinv)
// ---------------------------------------------------------------------------
__global__ __launch_bounds__(256) void k_rowstats(const float* __restrict__ STATS,
                                                  float2* __restrict__ MU2) {
  const int row = blockIdx.x * 256 + threadIdx.x;
  float s = 0.f, ss = 0.f;
#pragma unroll
  for (int i = 0; i < 16; ++i) {
    float2 p = *(const float2*)&STATS[((size_t)row << 5) + i * 2];
    s += p.x; ss += p.y;
  }
  const float mu = s * (1.f / CH);
  const float var = ss * (1.f / CH) - mu * mu;
  MU2[row] = make_float2(mu, 1.f / sqrtf(var + 1e-5f));
}

// ---------------------------------------------------------------------------
// K3: fused Z = relu(LN(H)) @ W2 + b2 -> per-head LSE -> Z, EXh, SELF.
// BM=64, BN=256, BK=32, 512 thr (8 waves 2Mx4N), 40KB dbuf LDS (2-3 blk/CU).
// A: tid<256 global->reg->LN->bf16->ds_write; B: waves 4-7 global_load_lds.
// Chunks/buf: A [0,256), B [256,1280)
// ---------------------------------------------------------------------------
__global__ __launch_bounds__(512) void k_gemm2(const u16* __restrict__ Hh,
                                               const u16* __restrict__ W2ht,
                                               const float* __restrict__ lng, const float* __restrict__ lnb,
                                               const float2* __restrict__ MU2,
                                               const float* __restrict__ b2,
                                               float* __restrict__ Z,
                                               u16* __restrict__ EXh,
                                               float* __restrict__ SELF) {
  __shared__ u16 sm[2][1280 * 8];   // 40 KB
  __shared__ float selfp[64][4];
  const int tid = threadIdx.x;
  const int lane = tid & 63, w = tid >> 6;
  const int wr = w >> 2, wc = w & 3;
  const int gm = blockIdx.x * 64;
  const int st_row = lane >> 2;
  const int st_k16 = (lane & 3) ^ ((lane >> 3) & 3);

  const int arow = tid >> 2, akc = tid & 3;
  const int pcA = (arow >> 4) * 64 + (arow & 15) * 4 + (akc ^ ((arow >> 1) & 3));
  float2 murv = make_float2(0.f, 0.f);
  const u16* gHh = nullptr;
  if (tid < 256) {
    murv = MU2[gm + arow];
    gHh = Hh + ((size_t)(gm + arow) << 11) + akc * 8;
  }

  f32x4 acc[2][4];
#pragma unroll
  for (int i = 0; i < 2; ++i)
#pragma unroll
    for (int j = 0; j < 4; ++j) acc[i][j] = (f32x4){0.f, 0.f, 0.f, 0.f};

  uint4 hwreg;
  auto A_LOAD = [&](int kt) {
    if (tid < 256) hwreg = *(const uint4*)(gHh + kt * 32);
  };
  auto B_STAGE = [&](int buf, int kt) {
    if (w >= 4) {
#pragma unroll
      for (int t = 0; t < 4; ++t) {
        const int f = (w - 4) * 256 + t * 64 + lane;   // [0,1024)
        const int grp = f >> 6;
        const int row = grp * 16 + st_row;
        gload16(W2ht + ((size_t)row << 11) + (kt << 5) + st_k16 * 8,
                &sm[buf][(size_t)(256 + f) * 8]);
      }
    }
  };
  auto LN_WRITE = [&](int buf, int kt) {
    if (tid < 256) {
      const int kb = kt * 32 + akc * 8;
      float4 g0 = *(const float4*)&lng[kb];
      float4 g1 = *(const float4*)&lng[kb + 4];
      float4 bb0 = *(const float4*)&lnb[kb];
      float4 bb1 = *(const float4*)&lnb[kb + 4];
      const float gg[8] = {g0.x, g0.y, g0.z, g0.w, g1.x, g1.y, g1.z, g1.w};
      const float bb[8] = {bb0.x, bb0.y, bb0.z, bb0.w, bb1.x, bb1.y, bb1.z, bb1.w};
      const unsigned hws[4] = {hwreg.x, hwreg.y, hwreg.z, hwreg.w};
      unsigned oh[4];
#pragma unroll
      for (int p = 0; p < 4; ++p) {
        u16 yh[2];
#pragma unroll
        for (int e = 0; e < 2; ++e) {
          const float h = bf2f((u16)(hws[p] >> (16 * e)));
          const float a1 = murv.y * gg[2 * p + e];
          const float y = fmaxf(fmaf(h, a1, bb[2 * p + e] - murv.x * a1), 0.f);
          yh[e] = f2bf(y);
        }
        oh[p] = (unsigned)yh[0] | ((unsigned)yh[1] << 16);
      }
      *(uint4*)&sm[buf][(size_t)pcA * 8] = make_uint4(oh[0], oh[1], oh[2], oh[3]);
    }
  };

  const int lr = lane & 15;
  const int rI = lr * 4 + ((lane >> 4) ^ ((lr >> 1) & 3));

  A_LOAD(0);
  B_STAGE(0, 0);
  LN_WRITE(0, 0);

  for (int kt = 0; kt < 64; ++kt) {
    __syncthreads();
    if (kt + 1 < 64) {
      A_LOAD(kt + 1);
      B_STAGE((kt + 1) & 1, kt + 1);
    }
    const u16* base = sm[kt & 1];
    short8 ah[2], bh[4];
#pragma unroll
    for (int i = 0; i < 2; ++i)
      ah[i] = *(const short8*)(base + ((wr * 2 + i) * 64 + rI) * 8);
#pragma unroll
    for (int j = 0; j < 4; ++j)
      bh[j] = *(const short8*)(base + (256 + (wc * 4 + j) * 64 + rI) * 8);
#pragma unroll
    for (int i = 0; i < 2; ++i)
#pragma unroll
      for (int j = 0; j < 4; ++j)
        acc[i][j] = __builtin_amdgcn_mfma_f32_16x16x32_bf16(ah[i], bh[j], acc[i][j], 0, 0, 0);
    if (kt + 1 < 64) LN_WRITE((kt + 1) & 1, kt + 1);
  }

  // fused epilogue: bias + per-head (64-col == this wave's wc) LSE
  const int cc = lane & 15;
  float bias[4];
#pragma unroll
  for (int j = 0; j < 4; ++j) bias[j] = b2[wc * 64 + j * 16 + cc];

#pragma unroll
  for (int i = 0; i < 2; ++i)
#pragma unroll
    for (int reg = 0; reg < 4; ++reg) {
      const int rl = wr * 32 + i * 16 + ((lane >> 4) << 2) + reg;   // row in [0,64)
      const int row = gm + rl;
      float z[4];
#pragma unroll
      for (int j = 0; j < 4; ++j) z[j] = acc[i][j][reg] + bias[j];
      float mx = fmaxf(fmaxf(z[0], z[1]), fmaxf(z[2], z[3]));
#pragma unroll
      for (int m = 1; m <= 8; m <<= 1) mx = fmaxf(mx, __shfl_xor(mx, m));
      float se = expf(z[0] - mx) + expf(z[1] - mx) + expf(z[2] - mx) + expf(z[3] - mx);
#pragma unroll
      for (int m = 1; m <= 8; m <<= 1) se += __shfl_xor(se, m);
      const float lse = mx + logf(se);
      float selfc = 0.f;
#pragma unroll
      for (int j = 0; j < 4; ++j) {
        const float p = z[j] - lse;
        const float e = expf(p);
        selfc += e * p;
        const size_t o = (size_t)row * DD + wc * 64 + j * 16 + cc;
        Z[o] = z[j];
        EXh[o] = f2bf(e);
      }
#pragma unroll
      for (int m = 1; m <= 8; m <<= 1) selfc += __shfl_xor(selfc, m);
      if (cc == 0) selfp[rl][wc] = selfc;
    }
  __syncthreads();
  if (tid < 64)
    SELF[gm + tid] = selfp[tid][0] + selfp[tid][1] + selfp[tid][2] + selfp[tid][3];
}

// ---------------------------------------------------------------------------
// K4: LEh = bf16(log(emb)), layout [1024][256]
// ---------------------------------------------------------------------------
__global__ __launch_bounds__(256) void k_prep_le(const float* __restrict__ E,
                                                 u16* __restrict__ LEh) {
  const size_t i = ((size_t)blockIdx.x * 256 + threadIdx.x) * 4;
  float4 v4 = *(const float4*)&E[i];
  const u16 h0 = f2bf(logf(v4.x)), h1 = f2bf(logf(v4.y));
  const u16 h2 = f2bf(logf(v4.z)), h3 = f2bf(logf(v4.w));
  *(uint2*)&LEh[i] = make_uint2((unsigned)h0 | ((unsigned)h1 << 16),
                                (unsigned)h2 | ((unsigned)h3 << 16));
}

// ---------------------------------------------------------------------------
// K5: dots = EX @ LE^T (single bf16 MFMA) with FUSED per-tile argmax.
// 128x128 tile, BK=32, K=256, DOUBLE-BUFFERED 32KB LDS. PV/PI [N][16].
// XCD-swizzled grid (1024): by=(hw&7)*16+(hw>>6), bx=(hw>>3)&7.
// Chunks/buf: EX [0,512), LE [512,1024)
// ---------------------------------------------------------------------------
__global__ __launch_bounds__(256) void k_dots(const u16* __restrict__ EXh,
                                              const u16* __restrict__ LEh,
                                              float* __restrict__ PV, int* __restrict__ PI) {
  __shared__ u16 sm[2][1024 * 8];   // 32 KB
  const int tid = threadIdx.x;
  const int lane = tid & 63, w = tid >> 6;
  const int wr = w >> 1, wc = w & 1;
  const int hw = blockIdx.x;
  const int by = (hw & 7) * 16 + (hw >> 6);   // [0,128)
  const int bx = (hw >> 3) & 7;               // [0,8)
  const int gm = by * 128, m0 = bx * 128;

  f32x4 acc[4][4];
#pragma unroll
  for (int i = 0; i < 4; ++i)
#pragma unroll
    for (int j = 0; j < 4; ++j) acc[i][j] = (f32x4){0.f, 0.f, 0.f, 0.f};

  auto STAGE = [&](int buf, int kt) {
#pragma unroll
    for (int t = 0; t < 4; ++t) {
      const int f = t * 256 + tid;            // [0,1024)
      const int mtx = f >> 9;                 // 0: EX, 1: LE (wave-uniform)
      const int wi = f & 511;
      const int grp = wi >> 6, s2 = wi & 63;
      const int rowbase = mtx ? m0 : gm;
      const int row = rowbase + grp * 16 + (s2 >> 2);
      const int k16 = (s2 & 3) ^ ((s2 >> 3) & 3);
      const u16* src = mtx ? LEh : EXh;
      gload16(src + ((size_t)row << 8) + (kt << 5) + k16 * 8,
              &sm[buf][(size_t)f * 8]);
    }
  };

  STAGE(0, 0);
  const int rI = (lane & 15) * 4 + ((lane >> 4) ^ ((lane >> 1) & 3));
  for (int kt = 0; kt < 8; ++kt) {
    __syncthreads();
    if (kt + 1 < 8) STAGE((kt + 1) & 1, kt + 1);
    const u16* base = sm[kt & 1];
    short8 eh[4], bh[4];
#pragma unroll
    for (int i = 0; i < 4; ++i) {
      eh[i] = *(const short8*)(base + ((wr * 4 + i) * 64 + rI) * 8);
      bh[i] = *(const short8*)(base + (512 + (wc * 4 + i) * 64 + rI) * 8);
    }
#pragma unroll
    for (int i = 0; i < 4; ++i)
#pragma unroll
      for (int j = 0; j < 4; ++j)
        acc[i][j] = __builtin_amdgcn_mfma_f32_16x16x32_bf16(eh[i], bh[j], acc[i][j], 0, 0, 0);
  }

  const int cc = lane & 15;
  const int mtile = bx * 2 + wc;
#pragma unroll
  for (int i = 0; i < 4; ++i)
#pragma unroll
    for (int reg = 0; reg < 4; ++reg) {
      float bv = acc[i][0][reg];
      int bi = m0 + wc * 64 + cc;
#pragma unroll
      for (int j = 1; j < 4; ++j) {
        const float v = acc[i][j][reg];
        if (v > bv) { bv = v; bi = m0 + wc * 64 + j * 16 + cc; }
      }
#pragma unroll
      for (int msk = 8; msk; msk >>= 1) {
        const float ov = __shfl_xor(bv, msk);
        const int   oi = __shfl_xor(bi, msk);
        if (ov > bv || (ov == bv && oi < bi)) { bv = ov; bi = oi; }
      }
      if (cc == 0) {
        const int row = gm + wr * 64 + i * 16 + ((lane >> 4) << 2) + reg;
        PV[row * 16 + mtile] = bv;
        PI[row * 16 + mtile] = bi;
      }
    }
}

// ---------------------------------------------------------------------------
// K6: per row: reduce 16 partials, KL = self - best, gather Q. Wave per row.
// ---------------------------------------------------------------------------
__global__ __launch_bounds__(256) void k_scan(const float* __restrict__ PV,
                                              const int* __restrict__ PI,
                                              const float* __restrict__ SELF,
                                              const float* __restrict__ E,
                                              float* __restrict__ Q,
                                              float* __restrict__ KL) {
  const int tid = threadIdx.x;
  const int lane = tid & 63;
  const int row = blockIdx.x * 4 + (tid >> 6);

  float bv = -1e30f;
  int bi = 0x7fffffff;
  if (lane < 16) { bv = PV[row * 16 + lane]; bi = PI[row * 16 + lane]; }
#pragma unroll
  for (int m = 32; m; m >>= 1) {
    const float ov = __shfl_xor(bv, m);
    const int   oi = __shfl_xor(bi, m);
    if (ov > bv || (ov == bv && oi < bi)) { bv = ov; bi = oi; }
  }
  if (lane == 0) KL[row] = SELF[row] - bv;
  float4 e4 = *(const float4*)&E[((size_t)bi << 8) + lane * 4];
  *(float4*)&Q[((size_t)row << 8) + lane * 4] = e4;
}

// ---------------------------------------------------------------------------
// K7: loss = 0.25/B * sum_n kl[n]*mask[n]
// ---------------------------------------------------------------------------
__global__ __launch_bounds__(256) void k_loss(const float* __restrict__ KL,
                                              const float* __restrict__ MASK,
                                              float* __restrict__ out) {
  __shared__ float red[4];
  const int tid = threadIdx.x;
  float s = 0.f;
  for (int i = tid; i < NROWS; i += 256) s += KL[i] * MASK[i];
#pragma unroll
  for (int m = 32; m; m >>= 1) s += __shfl_xor(s, m);
  if ((tid & 63) == 0) red[tid >> 6] = s;
  __syncthreads();
  if (tid == 0) out[0] = (red[0] + red[1] + red[2] + red[3]) * (0.25f / 16.f);
}

// ---------------------------------------------------------------------------
extern "C" void kernel_launch(void* const* d_in, const int* in_sizes, int n_in,
                              void* d_out, int out_size, void* d_ws, size_t ws_size,
                              hipStream_t stream) {
  const float* x     = (const float*)d_in[0];
  const float* masks = (const float*)d_in[1];
  const float* W1    = (const float*)d_in[2];
  const float* ln_g  = (const float*)d_in[3];
  const float* ln_b  = (const float*)d_in[4];
  const float* W2    = (const float*)d_in[5];
  const float* b2    = (const float*)d_in[6];
  const float* emb   = (const float*)d_in[7];

  float* z_out = (float*)d_out;
  float* q_out = z_out + (size_t)NROWS * DD;
  float* loss_out = z_out + 2 * (size_t)NROWS * DD;

  char* ws = (char*)d_ws;
  u16*   Hh   = (u16*)(ws);                    //  67,108,864 (16384x2048 bf16)
  u16*   W1ht = (u16*)(ws + 67108864);         //   2,097,152
  u16*   W2ht = (u16*)(ws + 69206016);         //   1,048,576
  u16*   LEh  = (u16*)(ws + 70254592);         //     524,288
  float* SELF = (float*)(ws + 70778880);       //      65,536
  float* KL   = (float*)(ws + 70844416);       //      65,536
  float2* MU2 = (float2*)(ws + 70909952);      //     131,072 -> end 71,041,024
  // overlays:
  float* PV   = (float*)(ws);                  //   1 MB (over Hh; H dead after gemm2)
  int*   PI   = (int*)(ws + 1048576);          //   1 MB
  float* STATS = (float*)q_out;                //   2 MB (q_out; consumed before EX written)
  u16*   EXh  = (u16*)q_out;                   //   8 MB (after STATS consumed)

  k_split_wT<<<dim3(64, 16), 256, 0, stream>>>(W1, W1ht, INCH, CH);
  k_split_wT<<<dim3(8, 64), 256, 0, stream>>>(W2, W2ht, CH, DD);
  k_prep_le<<<256, 256, 0, stream>>>(emb, LEh);

  k_gemm1<<<2048, 256, 0, stream>>>(x, W1ht, Hh, STATS);
  k_rowstats<<<NROWS / 256, 256, 0, stream>>>(STATS, MU2);
  k_gemm2<<<NROWS / 64, 512, 0, stream>>>(Hh, W2ht, ln_g, ln_b, MU2, b2,
                                          z_out, EXh, SELF);

  k_dots<<<1024, 256, 0, stream>>>(EXh, LEh, PV, PI);
  k_scan<<<4096, 256, 0, stream>>>(PV, PI, SELF, emb, q_out, KL);
  k_loss<<<1, 256, 0, stream>>>(KL, masks, loss_out);
}

// Round 15
// 192.738 us; speedup vs baseline: 2.2239x; 1.0428x over previous
//
#include <hip/hip_runtime.h>
#include <math.h>

#define NROWS 16384   // B*T
#define INCH  512
#define CH    2048
#define DD    256
#define MM    1024

typedef unsigned short u16;
typedef short short8 __attribute__((ext_vector_type(8)));
typedef float f32x4 __attribute__((ext_vector_type(4)));

__device__ __forceinline__ u16 f2bf(float f) {
  unsigned u = __float_as_uint(f);
  return (u16)((u + 0x7fffu + ((u >> 16) & 1u)) >> 16);
}
__device__ __forceinline__ float bf2f(u16 h) {
  return __uint_as_float(((unsigned)h) << 16);
}
__device__ __forceinline__ void gload16(const u16* g, u16* lds) {
  __builtin_amdgcn_global_load_lds((const __attribute__((address_space(1))) void*)g,
                                   (__attribute__((address_space(3))) void*)lds, 16, 0, 0);
}

// Coalesced-staging chunk mapping (16B chunks of 8 bf16 along K):
//   PC(row,kc) = (row>>4)*64 + (row&15)*4 + (kc ^ ((row>>1)&3))
//   frag read: chunk = group*64 + rI, rI = (lane&15)*4 + ((lane>>4)^((lane>>1)&3))

// ---------------------------------------------------------------------------
// K0: X fp32 -> bf16 (row-major, each element converted exactly once)
// ---------------------------------------------------------------------------
__global__ __launch_bounds__(256) void k_split_x(const float* __restrict__ x,
                                                 u16* __restrict__ xb) {
  const size_t i = ((size_t)blockIdx.x * 256 + threadIdx.x) * 8;
  float4 a = *(const float4*)(x + i);
  float4 b = *(const float4*)(x + i + 4);
  float v[8] = {a.x, a.y, a.z, a.w, b.x, b.y, b.z, b.w};
  unsigned hw[4];
#pragma unroll
  for (int p = 0; p < 4; ++p)
    hw[p] = (unsigned)f2bf(v[2 * p]) | ((unsigned)f2bf(v[2 * p + 1]) << 16);
  *(uint4*)(xb + i) = make_uint4(hw[0], hw[1], hw[2], hw[3]);
}

// src [R][C] fp32  ->  d [C][R] bf16 (transpose + round)
__global__ __launch_bounds__(256) void k_split_wT(const float* __restrict__ src,
                                                  u16* __restrict__ dh, int R, int C) {
  __shared__ float t[32][33];
  const int tx = threadIdx.x & 31, ty = threadIdx.x >> 5;
  const int c0 = blockIdx.x * 32, r0 = blockIdx.y * 32;
#pragma unroll
  for (int i = 0; i < 4; ++i)
    t[ty + i * 8][tx] = src[(size_t)(r0 + ty + i * 8) * C + c0 + tx];
  __syncthreads();
#pragma unroll
  for (int i = 0; i < 4; ++i) {
    float v = t[tx][ty + i * 8];
    dh[(size_t)(c0 + ty + i * 8) * R + r0 + tx] = f2bf(v);
  }
}

// ---------------------------------------------------------------------------
// K1: H = bf16(Xb @ W1).  m97 structure: 128x128 tile, BK=32, 4 waves (2x2),
// 32KB dbuf LDS. BOTH A and B staged via global_load_lds (zero VALU staging).
// XCD-swizzled grid (2048): y=(hw&7)*16+(hw>>3>>4), x=(hw>>3)&15.
// Epilogue: 4 slabs of 32 rows via fp32 [32][132] + row stats per 128-slice.
// Chunks/buf: A [0,512), B [512,1024)
// ---------------------------------------------------------------------------
__global__ __launch_bounds__(256) void k_gemm1(const u16* __restrict__ Xb,
                                               const u16* __restrict__ W1ht,
                                               u16* __restrict__ Hh,
                                               float* __restrict__ STATS) {
  __shared__ u16 sm[2][1024 * 8];   // 32 KB
  const int tid = threadIdx.x;
  const int lane = tid & 63, w = tid >> 6;
  const int wr = w >> 1, wc = w & 1;
  const int hw = blockIdx.x;
  const int u = hw >> 3;
  const int by = (hw & 7) * 16 + (u >> 4);   // [0,128)
  const int bx = u & 15;                     // [0,16)
  const int gm = by * 128, n0 = bx * 128;

  f32x4 acc[4][4];
#pragma unroll
  for (int i = 0; i < 4; ++i)
#pragma unroll
    for (int j = 0; j < 4; ++j) acc[i][j] = (f32x4){0.f, 0.f, 0.f, 0.f};

  auto STAGE = [&](int buf, int kt) {
#pragma unroll
    for (int t = 0; t < 4; ++t) {
      const int f = t * 256 + tid;            // [0,1024)
      const int isB = f >> 9;                 // wave-uniform
      const int wi = f & 511;
      const int grp = wi >> 6, s2 = wi & 63;
      const int row = (isB ? n0 : gm) + grp * 16 + (s2 >> 2);
      const int k16 = (s2 & 3) ^ ((s2 >> 3) & 3);
      const u16* src = isB ? W1ht : Xb;
      gload16(src + ((size_t)row << 9) + (kt << 5) + k16 * 8,
              &sm[buf][(size_t)f * 8]);
    }
  };

  STAGE(0, 0);
  const int lr = lane & 15;
  const int rI = lr * 4 + ((lane >> 4) ^ ((lr >> 1) & 3));
  for (int kt = 0; kt < 16; ++kt) {
    __syncthreads();
    if (kt + 1 < 16) STAGE((kt + 1) & 1, kt + 1);
    const u16* base = sm[kt & 1];
    short8 bh[4];
#pragma unroll
    for (int j = 0; j < 4; ++j)
      bh[j] = *(const short8*)(base + (size_t)(512 + (wc * 4 + j) * 64 + rI) * 8);
#pragma unroll
    for (int i = 0; i < 4; ++i) {
      short8 ah = *(const short8*)(base + (size_t)((wr * 4 + i) * 64 + rI) * 8);
#pragma unroll
      for (int j = 0; j < 4; ++j)
        acc[i][j] = __builtin_amdgcn_mfma_f32_16x16x32_bf16(ah, bh[j], acc[i][j], 0, 0, 0);
    }
  }

  // ---- epilogue: 4 slabs of 32 rows via fp32 [32][132] + row stats ----
  float* smf = (float*)&sm[0][0];
  const int rr = (lane >> 4) << 2, cc = lane & 15;
  const int lrow = tid >> 3, cg = tid & 7;
#pragma unroll
  for (int s = 0; s < 4; ++s) {
    __syncthreads();
    if (wr == (s >> 1)) {
#pragma unroll
      for (int ii = 0; ii < 2; ++ii) {
        const int i = (s & 1) * 2 + ii;
#pragma unroll
        for (int j = 0; j < 4; ++j)
#pragma unroll
          for (int reg = 0; reg < 4; ++reg)
            smf[(ii * 16 + rr + reg) * 132 + wc * 64 + j * 16 + cc] = acc[i][j][reg];
      }
    }
    __syncthreads();
    const int grow = gm + s * 32 + lrow;
    float s1 = 0.f, ss = 0.f;
    float v[16];
#pragma unroll
    for (int q = 0; q < 4; ++q)
      *(f32x4*)&v[q * 4] = *(const f32x4*)&smf[lrow * 132 + cg * 16 + q * 4];
#pragma unroll
    for (int e = 0; e < 16; ++e) { s1 += v[e]; ss += v[e] * v[e]; }
    unsigned hw2[8];
#pragma unroll
    for (int p = 0; p < 8; ++p) {
      const u16 h0 = f2bf(v[2 * p]), h1 = f2bf(v[2 * p + 1]);
      hw2[p] = (unsigned)h0 | ((unsigned)h1 << 16);
    }
    const size_t o = (size_t)grow * CH + n0 + cg * 16;
    *(uint4*)&Hh[o] = make_uint4(hw2[0], hw2[1], hw2[2], hw2[3]);
    *(uint4*)&Hh[o + 8] = make_uint4(hw2[4], hw2[5], hw2[6], hw2[7]);
#pragma unroll
    for (int m = 1; m <= 4; m <<= 1) { s1 += __shfl_xor(s1, m); ss += __shfl_xor(ss, m); }
    if (cg == 0)
      *(float2*)&STATS[(size_t)grow * 32 + bx * 2] = make_float2(s1, ss);
  }
}

// ---------------------------------------------------------------------------
// K2: reduce 16 slice-partials per row -> (mu, rinv)
// ---------------------------------------------------------------------------
__global__ __launch_bounds__(256) void k_rowstats(const float* __restrict__ STATS,
                                                  float2* __restrict__ MU2) {
  const int row = blockIdx.x * 256 + threadIdx.x;
  float s = 0.f, ss = 0.f;
#pragma unroll
  for (int i = 0; i < 16; ++i) {
    float2 p = *(const float2*)&STATS[((size_t)row << 5) + i * 2];
    s += p.x; ss += p.y;
  }
  const float mu = s * (1.f / CH);
  const float var = ss * (1.f / CH) - mu * mu;
  MU2[row] = make_float2(mu, 1.f / sqrtf(var + 1e-5f));
}

// ---------------------------------------------------------------------------
// K3: fused Z = relu(LN(H)) @ W2 + b2 -> per-head LSE -> Z, EXh, SELF.
// BM=64, BN=256, BK=32, 512 thr (8 waves 2Mx4N), 40KB dbuf LDS (2-3 blk/CU).
// A: tid<256 global->reg->LN->bf16->ds_write; B: waves 4-7 global_load_lds.
// Chunks/buf: A [0,256), B [256,1280)
// ---------------------------------------------------------------------------
__global__ __launch_bounds__(512) void k_gemm2(const u16* __restrict__ Hh,
                                               const u16* __restrict__ W2ht,
                                               const float* __restrict__ lng, const float* __restrict__ lnb,
                                               const float2* __restrict__ MU2,
                                               const float* __restrict__ b2,
                                               float* __restrict__ Z,
                                               u16* __restrict__ EXh,
                                               float* __restrict__ SELF) {
  __shared__ u16 sm[2][1280 * 8];   // 40 KB
  __shared__ float selfp[64][4];
  const int tid = threadIdx.x;
  const int lane = tid & 63, w = tid >> 6;
  const int wr = w >> 2, wc = w & 3;
  const int gm = blockIdx.x * 64;
  const int st_row = lane >> 2;
  const int st_k16 = (lane & 3) ^ ((lane >> 3) & 3);

  const int arow = tid >> 2, akc = tid & 3;
  const int pcA = (arow >> 4) * 64 + (arow & 15) * 4 + (akc ^ ((arow >> 1) & 3));
  float2 murv = make_float2(0.f, 0.f);
  const u16* gHh = nullptr;
  if (tid < 256) {
    murv = MU2[gm + arow];
    gHh = Hh + ((size_t)(gm + arow) << 11) + akc * 8;
  }

  f32x4 acc[2][4];
#pragma unroll
  for (int i = 0; i < 2; ++i)
#pragma unroll
    for (int j = 0; j < 4; ++j) acc[i][j] = (f32x4){0.f, 0.f, 0.f, 0.f};

  uint4 hwreg;
  auto A_LOAD = [&](int kt) {
    if (tid < 256) hwreg = *(const uint4*)(gHh + kt * 32);
  };
  auto B_STAGE = [&](int buf, int kt) {
    if (w >= 4) {
#pragma unroll
      for (int t = 0; t < 4; ++t) {
        const int f = (w - 4) * 256 + t * 64 + lane;   // [0,1024)
        const int grp = f >> 6;
        const int row = grp * 16 + st_row;
        gload16(W2ht + ((size_t)row << 11) + (kt << 5) + st_k16 * 8,
                &sm[buf][(size_t)(256 + f) * 8]);
      }
    }
  };
  auto LN_WRITE = [&](int buf, int kt) {
    if (tid < 256) {
      const int kb = kt * 32 + akc * 8;
      float4 g0 = *(const float4*)&lng[kb];
      float4 g1 = *(const float4*)&lng[kb + 4];
      float4 bb0 = *(const float4*)&lnb[kb];
      float4 bb1 = *(const float4*)&lnb[kb + 4];
      const float gg[8] = {g0.x, g0.y, g0.z, g0.w, g1.x, g1.y, g1.z, g1.w};
      const float bb[8] = {bb0.x, bb0.y, bb0.z, bb0.w, bb1.x, bb1.y, bb1.z, bb1.w};
      const unsigned hws[4] = {hwreg.x, hwreg.y, hwreg.z, hwreg.w};
      unsigned oh[4];
#pragma unroll
      for (int p = 0; p < 4; ++p) {
        u16 yh[2];
#pragma unroll
        for (int e = 0; e < 2; ++e) {
          const float h = bf2f((u16)(hws[p] >> (16 * e)));
          const float a1 = murv.y * gg[2 * p + e];
          const float y = fmaxf(fmaf(h, a1, bb[2 * p + e] - murv.x * a1), 0.f);
          yh[e] = f2bf(y);
        }
        oh[p] = (unsigned)yh[0] | ((unsigned)yh[1] << 16);
      }
      *(uint4*)&sm[buf][(size_t)pcA * 8] = make_uint4(oh[0], oh[1], oh[2], oh[3]);
    }
  };

  const int lr = lane & 15;
  const int rI = lr * 4 + ((lane >> 4) ^ ((lr >> 1) & 3));

  A_LOAD(0);
  B_STAGE(0, 0);
  LN_WRITE(0, 0);

  for (int kt = 0; kt < 64; ++kt) {
    __syncthreads();
    if (kt + 1 < 64) {
      A_LOAD(kt + 1);
      B_STAGE((kt + 1) & 1, kt + 1);
    }
    const u16* base = sm[kt & 1];
    short8 ah[2], bh[4];
#pragma unroll
    for (int i = 0; i < 2; ++i)
      ah[i] = *(const short8*)(base + ((wr * 2 + i) * 64 + rI) * 8);
#pragma unroll
    for (int j = 0; j < 4; ++j)
      bh[j] = *(const short8*)(base + (256 + (wc * 4 + j) * 64 + rI) * 8);
#pragma unroll
    for (int i = 0; i < 2; ++i)
#pragma unroll
      for (int j = 0; j < 4; ++j)
        acc[i][j] = __builtin_amdgcn_mfma_f32_16x16x32_bf16(ah[i], bh[j], acc[i][j], 0, 0, 0);
    if (kt + 1 < 64) LN_WRITE((kt + 1) & 1, kt + 1);
  }

  // fused epilogue: bias + per-head (64-col == this wave's wc) LSE
  const int cc = lane & 15;
  float bias[4];
#pragma unroll
  for (int j = 0; j < 4; ++j) bias[j] = b2[wc * 64 + j * 16 + cc];

#pragma unroll
  for (int i = 0; i < 2; ++i)
#pragma unroll
    for (int reg = 0; reg < 4; ++reg) {
      const int rl = wr * 32 + i * 16 + ((lane >> 4) << 2) + reg;   // row in [0,64)
      const int row = gm + rl;
      float z[4];
#pragma unroll
      for (int j = 0; j < 4; ++j) z[j] = acc[i][j][reg] + bias[j];
      float mx = fmaxf(fmaxf(z[0], z[1]), fmaxf(z[2], z[3]));
#pragma unroll
      for (int m = 1; m <= 8; m <<= 1) mx = fmaxf(mx, __shfl_xor(mx, m));
      float se = expf(z[0] - mx) + expf(z[1] - mx) + expf(z[2] - mx) + expf(z[3] - mx);
#pragma unroll
      for (int m = 1; m <= 8; m <<= 1) se += __shfl_xor(se, m);
      const float lse = mx + logf(se);
      float selfc = 0.f;
#pragma unroll
      for (int j = 0; j < 4; ++j) {
        const float p = z[j] - lse;
        const float e = expf(p);
        selfc += e * p;
        const size_t o = (size_t)row * DD + wc * 64 + j * 16 + cc;
        Z[o] = z[j];
        EXh[o] = f2bf(e);
      }
#pragma unroll
      for (int m = 1; m <= 8; m <<= 1) selfc += __shfl_xor(selfc, m);
      if (cc == 0) selfp[rl][wc] = selfc;
    }
  __syncthreads();
  if (tid < 64)
    SELF[gm + tid] = selfp[tid][0] + selfp[tid][1] + selfp[tid][2] + selfp[tid][3];
}

// ---------------------------------------------------------------------------
// K4: LEh = bf16(log(emb)), layout [1024][256]
// ---------------------------------------------------------------------------
__global__ __launch_bounds__(256) void k_prep_le(const float* __restrict__ E,
                                                 u16* __restrict__ LEh) {
  const size_t i = ((size_t)blockIdx.x * 256 + threadIdx.x) * 4;
  float4 v4 = *(const float4*)&E[i];
  const u16 h0 = f2bf(logf(v4.x)), h1 = f2bf(logf(v4.y));
  const u16 h2 = f2bf(logf(v4.z)), h3 = f2bf(logf(v4.w));
  *(uint2*)&LEh[i] = make_uint2((unsigned)h0 | ((unsigned)h1 << 16),
                                (unsigned)h2 | ((unsigned)h3 << 16));
}

// ---------------------------------------------------------------------------
// K5: dots = EX @ LE^T (single bf16 MFMA) with FUSED per-tile argmax.
// 128x128 tile, BK=32, K=256, DOUBLE-BUFFERED 32KB LDS. PV/PI [N][16].
// XCD-swizzled grid (1024): by=(hw&7)*16+(hw>>6), bx=(hw>>3)&7.
// ---------------------------------------------------------------------------
__global__ __launch_bounds__(256) void k_dots(const u16* __restrict__ EXh,
                                              const u16* __restrict__ LEh,
                                              float* __restrict__ PV, int* __restrict__ PI) {
  __shared__ u16 sm[2][1024 * 8];   // 32 KB
  const int tid = threadIdx.x;
  const int lane = tid & 63, w = tid >> 6;
  const int wr = w >> 1, wc = w & 1;
  const int hw = blockIdx.x;
  const int by = (hw & 7) * 16 + (hw >> 6);   // [0,128)
  const int bx = (hw >> 3) & 7;               // [0,8)
  const int gm = by * 128, m0 = bx * 128;

  f32x4 acc[4][4];
#pragma unroll
  for (int i = 0; i < 4; ++i)
#pragma unroll
    for (int j = 0; j < 4; ++j) acc[i][j] = (f32x4){0.f, 0.f, 0.f, 0.f};

  auto STAGE = [&](int buf, int kt) {
#pragma unroll
    for (int t = 0; t < 4; ++t) {
      const int f = t * 256 + tid;            // [0,1024)
      const int mtx = f >> 9;                 // 0: EX, 1: LE (wave-uniform)
      const int wi = f & 511;
      const int grp = wi >> 6, s2 = wi & 63;
      const int rowbase = mtx ? m0 : gm;
      const int row = rowbase + grp * 16 + (s2 >> 2);
      const int k16 = (s2 & 3) ^ ((s2 >> 3) & 3);
      const u16* src = mtx ? LEh : EXh;
      gload16(src + ((size_t)row << 8) + (kt << 5) + k16 * 8,
              &sm[buf][(size_t)f * 8]);
    }
  };

  STAGE(0, 0);
  const int rI = (lane & 15) * 4 + ((lane >> 4) ^ ((lane >> 1) & 3));
  for (int kt = 0; kt < 8; ++kt) {
    __syncthreads();
    if (kt + 1 < 8) STAGE((kt + 1) & 1, kt + 1);
    const u16* base = sm[kt & 1];
    short8 eh[4], bh[4];
#pragma unroll
    for (int i = 0; i < 4; ++i) {
      eh[i] = *(const short8*)(base + ((wr * 4 + i) * 64 + rI) * 8);
      bh[i] = *(const short8*)(base + (512 + (wc * 4 + i) * 64 + rI) * 8);
    }
#pragma unroll
    for (int i = 0; i < 4; ++i)
#pragma unroll
      for (int j = 0; j < 4; ++j)
        acc[i][j] = __builtin_amdgcn_mfma_f32_16x16x32_bf16(eh[i], bh[j], acc[i][j], 0, 0, 0);
  }

  const int cc = lane & 15;
  const int mtile = bx * 2 + wc;
#pragma unroll
  for (int i = 0; i < 4; ++i)
#pragma unroll
    for (int reg = 0; reg < 4; ++reg) {
      float bv = acc[i][0][reg];
      int bi = m0 + wc * 64 + cc;
#pragma unroll
      for (int j = 1; j < 4; ++j) {
        const float v = acc[i][j][reg];
        if (v > bv) { bv = v; bi = m0 + wc * 64 + j * 16 + cc; }
      }
#pragma unroll
      for (int msk = 8; msk; msk >>= 1) {
        const float ov = __shfl_xor(bv, msk);
        const int   oi = __shfl_xor(bi, msk);
        if (ov > bv || (ov == bv && oi < bi)) { bv = ov; bi = oi; }
      }
      if (cc == 0) {
        const int row = gm + wr * 64 + i * 16 + ((lane >> 4) << 2) + reg;
        PV[row * 16 + mtile] = bv;
        PI[row * 16 + mtile] = bi;
      }
    }
}

// ---------------------------------------------------------------------------
// K6: per row: reduce 16 partials, KL = self - best, gather Q. Wave per row.
// ---------------------------------------------------------------------------
__global__ __launch_bounds__(256) void k_scan(const float* __restrict__ PV,
                                              const int* __restrict__ PI,
                                              const float* __restrict__ SELF,
                                              const float* __restrict__ E,
                                              float* __restrict__ Q,
                                              float* __restrict__ KL) {
  const int tid = threadIdx.x;
  const int lane = tid & 63;
  const int row = blockIdx.x * 4 + (tid >> 6);

  float bv = -1e30f;
  int bi = 0x7fffffff;
  if (lane < 16) { bv = PV[row * 16 + lane]; bi = PI[row * 16 + lane]; }
#pragma unroll
  for (int m = 32; m; m >>= 1) {
    const float ov = __shfl_xor(bv, m);
    const int   oi = __shfl_xor(bi, m);
    if (ov > bv || (ov == bv && oi < bi)) { bv = ov; bi = oi; }
  }
  if (lane == 0) KL[row] = SELF[row] - bv;
  float4 e4 = *(const float4*)&E[((size_t)bi << 8) + lane * 4];
  *(float4*)&Q[((size_t)row << 8) + lane * 4] = e4;
}

// ---------------------------------------------------------------------------
// K7: loss = 0.25/B * sum_n kl[n]*mask[n]
// ---------------------------------------------------------------------------
__global__ __launch_bounds__(256) void k_loss(const float* __restrict__ KL,
                                              const float* __restrict__ MASK,
                                              float* __restrict__ out) {
  __shared__ float red[4];
  const int tid = threadIdx.x;
  float s = 0.f;
  for (int i = tid; i < NROWS; i += 256) s += KL[i] * MASK[i];
#pragma unroll
  for (int m = 32; m; m >>= 1) s += __shfl_xor(s, m);
  if ((tid & 63) == 0) red[tid >> 6] = s;
  __syncthreads();
  if (tid == 0) out[0] = (red[0] + red[1] + red[2] + red[3]) * (0.25f / 16.f);
}

// ---------------------------------------------------------------------------
extern "C" void kernel_launch(void* const* d_in, const int* in_sizes, int n_in,
                              void* d_out, int out_size, void* d_ws, size_t ws_size,
                              hipStream_t stream) {
  const float* x     = (const float*)d_in[0];
  const float* masks = (const float*)d_in[1];
  const float* W1    = (const float*)d_in[2];
  const float* ln_g  = (const float*)d_in[3];
  const float* ln_b  = (const float*)d_in[4];
  const float* W2    = (const float*)d_in[5];
  const float* b2    = (const float*)d_in[6];
  const float* emb   = (const float*)d_in[7];

  float* z_out = (float*)d_out;
  float* q_out = z_out + (size_t)NROWS * DD;
  float* loss_out = z_out + 2 * (size_t)NROWS * DD;

  char* ws = (char*)d_ws;
  u16*   Hh   = (u16*)(ws);                    //  67,108,864 (16384x2048 bf16)
  u16*   W1ht = (u16*)(ws + 67108864);         //   2,097,152
  u16*   W2ht = (u16*)(ws + 69206016);         //   1,048,576
  u16*   LEh  = (u16*)(ws + 70254592);         //     524,288
  float* SELF = (float*)(ws + 70778880);       //      65,536
  float* KL   = (float*)(ws + 70844416);       //      65,536
  float2* MU2 = (float2*)(ws + 70909952);      //     131,072
  u16*   Xb   = (u16*)(ws + 71041024);         //  16,777,216 -> end 87,818,240
  // overlays:
  float* PV   = (float*)(ws);                  //   1 MB (over Hh; H dead after gemm2)
  int*   PI   = (int*)(ws + 1048576);          //   1 MB
  float* STATS = (float*)q_out;                //   2 MB (q_out; consumed before EX written)
  u16*   EXh  = (u16*)q_out;                   //   8 MB (after STATS consumed)

  k_split_x<<<(NROWS * INCH) / 2048, 256, 0, stream>>>(x, Xb);
  k_split_wT<<<dim3(64, 16), 256, 0, stream>>>(W1, W1ht, INCH, CH);
  k_split_wT<<<dim3(8, 64), 256, 0, stream>>>(W2, W2ht, CH, DD);
  k_prep_le<<<256, 256, 0, stream>>>(emb, LEh);

  k_gemm1<<<2048, 256, 0, stream>>>(Xb, W1ht, Hh, STATS);
  k_rowstats<<<NROWS / 256, 256, 0, stream>>>(STATS, MU2);
  k_gemm2<<<NROWS / 64, 512, 0, stream>>>(Hh, W2ht, ln_g, ln_b, MU2, b2,
                                          z_out, EXh, SELF);

  k_dots<<<1024, 256, 0, stream>>>(EXh, LEh, PV, PI);
  k_scan<<<4096, 256, 0, stream>>>(PV, PI, SELF, emb, q_out, KL);
  k_loss<<<1, 256, 0, stream>>>(KL, masks, loss_out);
}